// Round 5
// baseline (249.740 us; speedup 1.0000x reference)
//
#include <hip/hip_runtime.h>
#include <math.h>

#define B_   4
#define S_   2048
#define H_   1024
#define NH   16
#define HD   64
#define T_   (B_ * S_)       // 8192 tokens
#define NCH  16              // kv S-chunks

typedef unsigned short u16;
typedef __bf16 bf16x8 __attribute__((ext_vector_type(8)));
typedef float  f32x4  __attribute__((ext_vector_type(4)));

// ---------------------------------------------------------------------------
__device__ __forceinline__ float elu_k(float x) {
    return (x > 0.f ? x : (expf(x) - 1.f)) + 1.000001f;
}

__device__ __forceinline__ u16 f2bf(float x) {
    union { float f; unsigned int u; } v; v.f = x;
    unsigned int r = v.u + 0x7FFFu + ((v.u >> 16) & 1u);
    return (u16)(r >> 16);
}

__device__ __forceinline__ float bfl(unsigned int u) {
    union { unsigned int u; float f; } v; v.u = u << 16; return v.f;
}
__device__ __forceinline__ float bfh(unsigned int u) {
    union { unsigned int u; float f; } v; v.u = u & 0xFFFF0000u; return v.f;
}

// async global->LDS, 16 B/lane; LDS side uses lane0's base + lane*16,
// global side is per-lane.
__device__ __forceinline__ void async_load16(const u16* g, u16* l) {
    __builtin_amdgcn_global_load_lds(
        (const __attribute__((address_space(1))) void*)g,
        (__attribute__((address_space(3))) void*)l,
        16, 0, 0);
}

// ---------------------------------------------------------------------------
// prep: rope tables + packed bias + coeff, one launch.
__global__ __launch_bounds__(256) void prep_kernel(
    const float* __restrict__ decay, const float* __restrict__ gate,
    float* __restrict__ coeff, float* __restrict__ cosT,
    float* __restrict__ sinT, const float* __restrict__ bq,
    const float* __restrict__ bk, const float* __restrict__ bv,
    float* __restrict__ bqkv) {
    int idx = blockIdx.x * 256 + threadIdx.x;
    if (idx < S_ * 32) {
        int s = idx >> 5, i = idx & 31;
        float inv = powf(10000.f, -(2.f * (float)i) / 64.f);
        float f = (float)s * inv;
        cosT[idx] = cosf(f);
        sinT[idx] = sinf(f);
    } else if (idx < S_ * 32 + 3072) {
        int i = idx - S_ * 32;
        bqkv[i] = (i < 1024) ? bq[i] : (i < 2048) ? bk[i - 1024] : bv[i - 2048];
    } else if (idx == S_ * 32 + 3072) {
        float g0 = gate[0], g1 = gate[1], g2 = gate[2];
        float mx = fmaxf(g0, fmaxf(g1, g2));
        float e0 = expf(g0 - mx), e1 = expf(g1 - mx), e2 = expf(g2 - mx);
        float inv = 1.f / (e0 + e1 + e2);
        float es[3] = {e0, e1, e2};
        float c = 0.f;
        for (int m = 0; m < 3; m++) {
            float ds = 1.f / (1.f + expf(-decay[m]));
            c += es[m] * inv * (1.f - ds);
        }
        *coeff = c;
    }
}

// ---------------------------------------------------------------------------
// Fused hs->bf16 convert + gate gemv. One block per token.
__global__ __launch_bounds__(256) void cvt_gate_kernel(
    const float* __restrict__ hs, const float* __restrict__ Wg,
    const float* __restrict__ bg, u16* __restrict__ hsb,
    float* __restrict__ gbuf) {
    int t = blockIdx.x;
    int i = threadIdx.x;
    float4 f = ((const float4*)(hs + (size_t)t * H_))[i];
    float4 w = ((const float4*)Wg)[i];
    ushort4 u;
    u.x = f2bf(f.x); u.y = f2bf(f.y); u.z = f2bf(f.z); u.w = f2bf(f.w);
    ((ushort4*)(hsb + (size_t)t * H_))[i] = u;
    float s = f.x * w.x + f.y * w.y + f.z * w.z + f.w * w.w;
#pragma unroll
    for (int off = 32; off > 0; off >>= 1) s += __shfl_down(s, off);
    __shared__ float wsum[4];
    if ((i & 63) == 0) wsum[i >> 6] = s;
    __syncthreads();
    if (i == 0) {
        float tot = wsum[0] + wsum[1] + wsum[2] + wsum[3];
        gbuf[t] = 1.f / (1.f + expf(-(tot + bg[0])));
    }
}

// ---------------------------------------------------------------------------
// Transpose+convert weights: Wt[w*1024 + n][k] = bf16(W_w[k][n])
__global__ __launch_bounds__(256) void pack_w_kernel(
    const float* __restrict__ Wq, const float* __restrict__ Wk,
    const float* __restrict__ Wv, const float* __restrict__ Wo,
    u16* __restrict__ Wt) {
    __shared__ u16 tile[64][65];
    const float* W = (blockIdx.z == 0) ? Wq :
                     (blockIdx.z == 1) ? Wk :
                     (blockIdx.z == 2) ? Wv : Wo;
    int nt = blockIdx.x * 64, kt = blockIdx.y * 64;
    int tid = threadIdx.x;
#pragma unroll
    for (int it = 0; it < 16; it++) {
        int i = it * 256 + tid;
        int kr = i >> 6, nc = i & 63;
        tile[kr][nc] = f2bf(W[(size_t)(kt + kr) * H_ + nt + nc]);
    }
    __syncthreads();
    size_t wbase = (size_t)blockIdx.z * H_;
#pragma unroll
    for (int it = 0; it < 16; it++) {
        int i = it * 256 + tid;
        int nr = i >> 6, kc = i & 63;
        Wt[(wbase + nt + nr) * H_ + kt + kc] = tile[kc][nr];
    }
}

// ---------------------------------------------------------------------------
// GEMM core v5: R3's geometry + counted-vmcnt pipeline (isolated change).
// BM=256, BN=128, BK=64, 512 thr = 8 waves (4M x 2N), per-wave C = 64x64.
// LDS 96 KiB dbuf: A [2][256][64] (0..32768 u16), B [2][128][64]
// (32768..49152 u16).  1 block/CU; grids are exact multiples of 256.
// T2 chunk-XOR swizzle (involution chunk ^= row&7): stage pre-swizzles the
// GLOBAL source 16B-chunk (LDS dest linear for global_load_lds), reads apply
// the same XOR -> conflict-free ds_read_b128 (measured 0 in R1-R4).
//
// COUNTED-vmcnt pipeline (m218 lever, now at the good geometry):
//   prologue: STAGE(0) -> buf0.
//   tile n:  STAGE(n+1) -> buf[(n+1)&1]      (6 loads/wave, via persistent
//                                             pointers advanced +64/tile)
//            s_waitcnt vmcnt(6)  <- stage(n) landed, stage(n+1) IN FLIGHT
//            s_barrier           <- everyone's stage(n) landed
//            16 ds_reads (kk0 x8 | sched_barrier | kk1 x8)
//            lgkmcnt(8) ; MFMA kk0 (16)  <- kk1 reads land under this
//            lgkmcnt(0) ; MFMA kk1 (16)
//            s_barrier           <- all reads of buf[n&1] done
//   Stage issue->wait distance = one full tile (~3400 cy) > HBM ~900 cy;
//   vmcnt never drains to 0 mid-loop.
// Race ledger:
//  - stage(n+2) writes buf[n&1]; its readers (tile n) drained per-wave at
//    lgkmcnt(0) before tile n's trailing barrier < stage(n+2) issue (tile n+1).
//  - readers of buf[(n+1)&1] sit behind per-wave vmcnt(6) + leading barrier.

#define STAGE6(AST, BST)                                                      \
    {                                                                         \
        async_load16(pa0, &sAB[(AST) + wid * 2048 + lane * 8]);               \
        async_load16(pa1, &sAB[(AST) + wid * 2048 + 512 + lane * 8]);         \
        async_load16(pa2, &sAB[(AST) + wid * 2048 + 1024 + lane * 8]);        \
        async_load16(pa3, &sAB[(AST) + wid * 2048 + 1536 + lane * 8]);        \
        async_load16(pb0, &sAB[(BST) + wid * 1024 + lane * 8]);               \
        async_load16(pb1, &sAB[(BST) + wid * 1024 + 512 + lane * 8]);         \
        pa0 += 64; pa1 += 64; pa2 += 64; pa3 += 64; pb0 += 64; pb1 += 64;     \
    }

#define KBODY(ARD, BRD, AWR, BWR, STG)                                        \
    {                                                                         \
        if (STG) {                                                            \
            STAGE6(AWR, BWR)                                                  \
            asm volatile("s_waitcnt vmcnt(6)" ::: "memory");                  \
        } else {                                                              \
            asm volatile("s_waitcnt vmcnt(0)" ::: "memory");                  \
        }                                                                     \
        __builtin_amdgcn_s_barrier();                                         \
        asm volatile("" ::: "memory");                                        \
        const u16* Ab = &sAB[(ARD) + (wr * 64 + l15) * 64];                   \
        const u16* Bb = &sAB[(BRD) + (wc * 64 + l15) * 64];                   \
        bf16x8 a0[4], b0[4], a1[4], b1[4];                                    \
        _Pragma("unroll")                                                     \
        for (int mi = 0; mi < 4; mi++)                                        \
            a0[mi] = *(const bf16x8*)&Ab[mi * 1024 + sw0];                    \
        _Pragma("unroll")                                                     \
        for (int nj = 0; nj < 4; nj++)                                        \
            b0[nj] = *(const bf16x8*)&Bb[nj * 1024 + sw0];                    \
        __builtin_amdgcn_sched_barrier(0);                                    \
        _Pragma("unroll")                                                     \
        for (int mi = 0; mi < 4; mi++)                                        \
            a1[mi] = *(const bf16x8*)&Ab[mi * 1024 + sw1];                    \
        _Pragma("unroll")                                                     \
        for (int nj = 0; nj < 4; nj++)                                        \
            b1[nj] = *(const bf16x8*)&Bb[nj * 1024 + sw1];                    \
        asm volatile("s_waitcnt lgkmcnt(8)" ::: "memory");                    \
        __builtin_amdgcn_sched_barrier(0);                                    \
        __builtin_amdgcn_s_setprio(1);                                        \
        _Pragma("unroll")                                                     \
        for (int mi = 0; mi < 4; mi++)                                        \
            _Pragma("unroll")                                                 \
            for (int nj = 0; nj < 4; nj++)                                    \
                acc[mi][nj] = __builtin_amdgcn_mfma_f32_16x16x32_bf16(        \
                    a0[mi], b0[nj], acc[mi][nj], 0, 0, 0);                    \
        __builtin_amdgcn_s_setprio(0);                                        \
        asm volatile("s_waitcnt lgkmcnt(0)" ::: "memory");                    \
        __builtin_amdgcn_sched_barrier(0);                                    \
        __builtin_amdgcn_s_setprio(1);                                        \
        _Pragma("unroll")                                                     \
        for (int mi = 0; mi < 4; mi++)                                        \
            _Pragma("unroll")                                                 \
            for (int nj = 0; nj < 4; nj++)                                    \
                acc[mi][nj] = __builtin_amdgcn_mfma_f32_16x16x32_bf16(        \
                    a1[mi], b1[nj], acc[mi][nj], 0, 0, 0);                    \
        __builtin_amdgcn_s_setprio(0);                                        \
        __builtin_amdgcn_sched_barrier(0);                                    \
        asm volatile("" ::: "memory");                                        \
        __builtin_amdgcn_s_barrier();                                         \
    }

// A bufs at u16 offsets 0 / 16384; B bufs at 32768 / 40960.
#define KLOOP(A_, Bt_)                                                        \
    const u16* pa0 = A_ + (size_t)(bm + wid * 32 +  0 + ln8) * 1024 + scs8;   \
    const u16* pa1 = A_ + (size_t)(bm + wid * 32 +  8 + ln8) * 1024 + scs8;   \
    const u16* pa2 = A_ + (size_t)(bm + wid * 32 + 16 + ln8) * 1024 + scs8;   \
    const u16* pa3 = A_ + (size_t)(bm + wid * 32 + 24 + ln8) * 1024 + scs8;   \
    const u16* pb0 = Bt_ + (size_t)(bn + wid * 16 +  0 + ln8) * 1024 + scs8;  \
    const u16* pb1 = Bt_ + (size_t)(bn + wid * 16 +  8 + ln8) * 1024 + scs8;  \
    STAGE6(0, 32768)                                                          \
    for (int it = 0; it < 7; ++it) {                                          \
        KBODY(0, 32768, 16384, 40960, 1)      /* even tile: read buf0 */      \
        KBODY(16384, 40960, 0, 32768, 1)      /* odd tile: read buf1 */       \
    }                                                                         \
    KBODY(0, 32768, 16384, 40960, 1)          /* tile 14, stages 15 */        \
    KBODY(16384, 40960, 0, 32768, 0)          /* tile 15, drain */

// bijective XCD swizzle (nwg % 8 == 0 for both GEMM grids): each XCD gets a
// contiguous chunk of row-major block ids -> its A-row-panels stay in its L2.
#define XCD_SWIZZLE(BM_, BN_)                                                 \
    const int nwg = gridDim.x * gridDim.y;                                    \
    int orig = blockIdx.y * gridDim.x + blockIdx.x;                           \
    int wg = (orig & 7) * (nwg >> 3) + (orig >> 3);                           \
    const int bm = (wg / gridDim.x) * (BM_), bn = (wg % gridDim.x) * (BN_);

// ---------------------------------------------------------------------------
// QKV GEMM with fused rope+elu+mask epilogue -> bf16 head-major qb/kb/vb.
// grid (24, 32) = 768 blocks = 3.0 perfect rounds at 1 block/CU.
__global__ __launch_bounds__(512, 2) void gemm_qkv_kernel(
    const u16* __restrict__ A, const u16* __restrict__ Bt,
    const float* __restrict__ bias, const float* __restrict__ mask,
    const float* __restrict__ cosT, const float* __restrict__ sinT,
    u16* __restrict__ qb, u16* __restrict__ kb, u16* __restrict__ vb) {
    __shared__ u16 sAB[49152];                 // 96 KiB
    const int tid  = threadIdx.x;
    const int wid  = tid >> 6, lane = tid & 63;
    const int wr = wid >> 1, wc = wid & 1;
    const int l15 = lane & 15, quad = lane >> 4;
    const int ln8 = lane >> 3;
    const int scs8 = ((lane & 7) ^ ln8) * 8;
    const int sw0 = (quad ^ (l15 & 7)) * 8;
    const int sw1 = ((4 + quad) ^ (l15 & 7)) * 8;
    XCD_SWIZZLE(256, 128)

    f32x4 acc[4][4];
#pragma unroll
    for (int i = 0; i < 4; i++)
#pragma unroll
        for (int j = 0; j < 4; j++) acc[i][j] = {0.f, 0.f, 0.f, 0.f};

    KLOOP(A, Bt)

    // ---- fused epilogue
    const int colbase = bn + wc * 64;          // multiple of 64
    const int region  = colbase >> 10;         // 0=q 1=k 2=v
    const int nh      = (colbase & 1023) >> 6;
    float bc[4];
#pragma unroll
    for (int nj = 0; nj < 4; nj++) bc[nj] = bias[colbase + nj * 16 + l15];
    u16* outp = (region == 0) ? qb : (region == 1) ? kb : vb;

#pragma unroll
    for (int mi = 0; mi < 4; mi++) {
#pragma unroll
        for (int r = 0; r < 4; r++) {
            int row = bm + wr * 64 + mi * 16 + quad * 4 + r;
            int b = row >> 11, s = row & (S_ - 1);
            size_t obase = ((size_t)(b * 16 + nh) * S_ + s) * 64;
            if (region < 2) {
                float mfac = (region == 0) ? 0.125f : mask[row];
#pragma unroll
                for (int p = 0; p < 2; p++) {
                    int d1 = p * 16 + l15;
                    float c  = cosT[s * 32 + d1];
                    float sn = sinT[s * 32 + d1];
                    float x1 = acc[mi][p][r]     + bc[p];
                    float x2 = acc[mi][p + 2][r] + bc[p + 2];
                    float r1 = x1 * c - x2 * sn;
                    float r2 = x2 * c + x1 * sn;
                    outp[obase + d1]      = f2bf(elu_k(r1) * mfac);
                    outp[obase + d1 + 32] = f2bf(elu_k(r2) * mfac);
                }
            } else {
                float mfac = mask[row];
#pragma unroll
                for (int nj = 0; nj < 4; nj++)
                    outp[obase + nj * 16 + l15] =
                        f2bf((acc[mi][nj][r] + bc[nj]) * mfac);
            }
        }
    }
}

// ---------------------------------------------------------------------------
// Output projection GEMM: C fp32 = A @ Bt^T + bias.
// grid (8, 32) = 256 blocks = 1.0 perfect round at 1 block/CU.
__global__ __launch_bounds__(512, 2) void gemm_out_kernel(
    const u16* __restrict__ A, const u16* __restrict__ Bt,
    const float* __restrict__ bias, float* __restrict__ C, int N) {
    __shared__ u16 sAB[49152];                 // 96 KiB
    const int tid  = threadIdx.x;
    const int wid  = tid >> 6, lane = tid & 63;
    const int wr = wid >> 1, wc = wid & 1;
    const int l15 = lane & 15, quad = lane >> 4;
    const int ln8 = lane >> 3;
    const int scs8 = ((lane & 7) ^ ln8) * 8;
    const int sw0 = (quad ^ (l15 & 7)) * 8;
    const int sw1 = ((4 + quad) ^ (l15 & 7)) * 8;
    XCD_SWIZZLE(256, 128)

    f32x4 acc[4][4];
#pragma unroll
    for (int i = 0; i < 4; i++)
#pragma unroll
        for (int j = 0; j < 4; j++) acc[i][j] = {0.f, 0.f, 0.f, 0.f};

    KLOOP(A, Bt)

#pragma unroll
    for (int mi = 0; mi < 4; mi++) {
#pragma unroll
        for (int nj = 0; nj < 4; nj++) {
            int col = bn + wc * 64 + nj * 16 + l15;
            float bcol = bias[col];
#pragma unroll
            for (int r = 0; r < 4; r++) {
                int row = bm + wr * 64 + mi * 16 + quad * 4 + r;
                C[(size_t)row * N + col] = acc[mi][nj][r] + bcol;
            }
        }
    }
}

// ---------------------------------------------------------------------------
// kv partials from bf16 head-major k,v: grid (64 bn, NCH).
__global__ __launch_bounds__(256) void kv_part_kernel(
    const u16* __restrict__ kb, const u16* __restrict__ vb,
    float* __restrict__ kvpart, float* __restrict__ kspart) {
    int bn = blockIdx.x;
    const int rows = S_ / NCH;              // 128
    int s0 = blockIdx.y * rows;
    int tid = threadIdx.x;
    int ti = tid >> 4, tj = tid & 15;
    __shared__ float ks[16][64], vs[16][64];
    float acc[4][4] = {};
    float ksacc = 0.f;
    const u16* kbase = kb + (size_t)bn * (S_ * 64) + (size_t)s0 * 64;
    const u16* vbase = vb + (size_t)bn * (S_ * 64) + (size_t)s0 * 64;
    for (int ss = 0; ss < rows; ss += 16) {
        {
            int half = tid >> 7;
            int c = tid & 127;
            int rr = c >> 3, col = (c & 7) * 8;
            const u16* src = (half ? vbase : kbase) + (size_t)(ss + rr) * 64 + col;
            uint4 raw = *(const uint4*)src;
            float* dst = half ? &vs[rr][col] : &ks[rr][col];
            dst[0] = bfl(raw.x); dst[1] = bfh(raw.x);
            dst[2] = bfl(raw.y); dst[3] = bfh(raw.y);
            dst[4] = bfl(raw.z); dst[5] = bfh(raw.z);
            dst[6] = bfl(raw.w); dst[7] = bfh(raw.w);
        }
        __syncthreads();
#pragma unroll
        for (int r = 0; r < 16; r++) {
            float a[4], bb[4];
#pragma unroll
            for (int i = 0; i < 4; i++) a[i] = ks[r][ti * 4 + i];
#pragma unroll
            for (int j = 0; j < 4; j++) bb[j] = vs[r][tj * 4 + j];
#pragma unroll
            for (int i = 0; i < 4; i++)
#pragma unroll
                for (int j = 0; j < 4; j++)
                    acc[i][j] = fmaf(a[i], bb[j], acc[i][j]);
        }
        if (tid < 64) {
#pragma unroll
            for (int r = 0; r < 16; r++) ksacc += ks[r][tid];
        }
        __syncthreads();
    }
    size_t obase = ((size_t)blockIdx.y * 64 + bn) * 4096;
#pragma unroll
    for (int i = 0; i < 4; i++)
#pragma unroll
        for (int j = 0; j < 4; j++)
            kvpart[obase + (size_t)(ti * 4 + i) * 64 + tj * 4 + j] = acc[i][j];
    if (tid < 64)
        kspart[((size_t)blockIdx.y * 64 + bn) * 64 + tid] = ksacc;
}

// sum NCH partials for kv (262144) and ksum (4096) in one launch
__global__ __launch_bounds__(256) void reduce_part_kernel(
    const float* __restrict__ kvpart, const float* __restrict__ kspart,
    float* __restrict__ kvb, float* __restrict__ ksum) {
    int i = blockIdx.x * 256 + threadIdx.x;
    if (i < 262144) {
        float s = 0.f;
#pragma unroll
        for (int c = 0; c < NCH; c++) s += kvpart[(size_t)c * 262144 + i];
        kvb[i] = s;
    } else if (i < 262144 + 4096) {
        int j = i - 262144;
        float s = 0.f;
#pragma unroll
        for (int c = 0; c < NCH; c++) s += kspart[(size_t)c * 4096 + j];
        ksum[j] = s;
    }
}

// ---------------------------------------------------------------------------
// MFMA combine: per (b,n), num = Q[256x64] @ kv[64x64], den via ksum column.
__global__ __launch_bounds__(256) void combine_kernel(
    const u16* __restrict__ qb, const float* __restrict__ kvb,
    const float* __restrict__ ksum, const float* __restrict__ g,
    const float* __restrict__ coeffp, u16* __restrict__ cmb) {
    int bn = blockIdx.x;
    int b = bn >> 4, n = bn & 15;
    __shared__ u16 qs[256 * 72];
    __shared__ u16 kvT[64 * 72];
    __shared__ u16 ksl[128];
    int tid = threadIdx.x;
    int s0 = blockIdx.y * 256;

    const u16* qsrc = qb + (size_t)bn * (S_ * 64) + (size_t)s0 * 64;
    for (int c = tid; c < 2048; c += 256) {
        int t = c >> 3, k8 = (c & 7) * 8;
        float4 tmp = *(const float4*)(qsrc + (size_t)c * 8);
        *(float4*)&qs[t * 72 + k8] = tmp;
    }
    for (int c = tid; c < 1024; c += 256) {
        int i = c >> 4, d4 = (c & 15) * 4;
        float4 kvv = *(const float4*)&kvb[(size_t)bn * 4096 + i * 64 + d4];
        kvT[(d4 + 0) * 72 + i] = f2bf(kvv.x);
        kvT[(d4 + 1) * 72 + i] = f2bf(kvv.y);
        kvT[(d4 + 2) * 72 + i] = f2bf(kvv.z);
        kvT[(d4 + 3) * 72 + i] = f2bf(kvv.w);
    }
    if (tid < 64)        ksl[tid] = f2bf(ksum[bn * 64 + tid]);
    else if (tid < 128)  ksl[tid] = 0;
    __syncthreads();

    int wave = tid >> 6, lane = tid & 63;
    int l15 = lane & 15, quad = lane >> 4;
    int wt = wave * 64;

    int ko0 = (l15 == 0) ? quad * 8      : 64;
    int ko1 = (l15 == 0) ? 32 + quad * 8 : 64;
    bf16x8 ksf0 = *(const bf16x8*)&ksl[ko0];
    bf16x8 ksf1 = *(const bf16x8*)&ksl[ko1];

    bf16x8 bfr0[4], bfr1[4];
#pragma unroll
    for (int nj = 0; nj < 4; nj++) {
        bfr0[nj] = *(const bf16x8*)&kvT[(nj * 16 + l15) * 72 + quad * 8];
        bfr1[nj] = *(const bf16x8*)&kvT[(nj * 16 + l15) * 72 + 32 + quad * 8];
    }

    f32x4 acc[4][4], dacc[4];
#pragma unroll
    for (int i = 0; i < 4; i++) {
        dacc[i] = {0.f, 0.f, 0.f, 0.f};
#pragma unroll
        for (int j = 0; j < 4; j++) acc[i][j] = {0.f, 0.f, 0.f, 0.f};
    }

#pragma unroll
    for (int mi = 0; mi < 4; mi++) {
        bf16x8 a0 = *(const bf16x8*)&qs[(wt + mi * 16 + l15) * 72 + quad * 8];
        bf16x8 a1 = *(const bf16x8*)&qs[(wt + mi * 16 + l15) * 72 + 32 + quad * 8];
        dacc[mi] = __builtin_amdgcn_mfma_f32_16x16x32_bf16(a0, ksf0, dacc[mi], 0, 0, 0);
        dacc[mi] = __builtin_amdgcn_mfma_f32_16x16x32_bf16(a1, ksf1, dacc[mi], 0, 0, 0);
#pragma unroll
        for (int nj = 0; nj < 4; nj++) {
            acc[mi][nj] = __builtin_amdgcn_mfma_f32_16x16x32_bf16(
                a0, bfr0[nj], acc[mi][nj], 0, 0, 0);
            acc[mi][nj] = __builtin_amdgcn_mfma_f32_16x16x32_bf16(
                a1, bfr1[nj], acc[mi][nj], 0, 0, 0);
        }
    }

    float coeff = *coeffp;
#pragma unroll
    for (int mi = 0; mi < 4; mi++) {
#pragma unroll
        for (int r = 0; r < 4; r++) {
            int s = s0 + wt + mi * 16 + quad * 4 + r;
            int t = b * S_ + s;
            float den = __shfl(dacc[mi][r], lane & 48) + 1e-6f;
            float gv = g[t];
            float w1 = gv / den + (1.f - gv) * coeff;
#pragma unroll
            for (int nj = 0; nj < 4; nj++) {
                int d = nj * 16 + l15;
                cmb[(size_t)t * H_ + n * 64 + d] = f2bf(acc[mi][nj][r] * w1);
            }
        }
    }
}

// ---------------------------------------------------------------------------
extern "C" void kernel_launch(void* const* d_in, const int* in_sizes, int n_in,
                              void* d_out, int out_size, void* d_ws, size_t ws_size,
                              hipStream_t stream) {
    const float* hs    = (const float*)d_in[0];
    const float* mask  = (const float*)d_in[1];
    const float* Wq    = (const float*)d_in[2];
    const float* bq    = (const float*)d_in[3];
    const float* Wk    = (const float*)d_in[4];
    const float* bk    = (const float*)d_in[5];
    const float* Wv    = (const float*)d_in[6];
    const float* bv    = (const float*)d_in[7];
    const float* Wo    = (const float*)d_in[8];
    const float* bo    = (const float*)d_in[9];
    const float* Wg    = (const float*)d_in[10];
    const float* bg    = (const float*)d_in[11];
    const float* decay = (const float*)d_in[12];
    const float* gate  = (const float*)d_in[13];
    float* out = (float*)d_out;

    // ---- workspace layout
    float* ws     = (float*)d_ws;
    float* kvb    = ws;                         // 262144
    float* ksum   = kvb + 262144;               // 4096
    float* gbuf   = ksum + 4096;                // 8192
    float* coeff  = gbuf + 8192;                // 64
    float* cosT   = coeff + 64;                 // 65536
    float* sinT   = cosT + 65536;               // 65536
    float* bqkv   = sinT + 65536;               // 3072 (+pad to 4096)
    float* kspart = bqkv + 4096;                // NCH*4096 = 65536
    float* kvpart = kspart + 65536;             // NCH*262144 = 4194304
    u16*   hsb    = (u16*)(kvpart + 4194304);   // T*1024
    u16*   Wt     = hsb + (size_t)T_ * H_;      // 4096*1024
    u16*   WoT    = Wt + (size_t)3072 * H_;
    u16*   qb     = Wt + (size_t)4096 * H_;     // T*1024 head-major
    u16*   kb     = qb + (size_t)T_ * H_;
    u16*   vb     = kb + (size_t)T_ * H_;
    u16*   cmb    = vb + (size_t)T_ * H_;

    prep_kernel<<<(S_ * 32 + 3072 + 256) / 256 + 1, 256, 0, stream>>>(
        decay, gate, coeff, cosT, sinT, bq, bk, bv, bqkv);
    cvt_gate_kernel<<<T_, 256, 0, stream>>>(hs, Wg, bg, hsb, gbuf);
    pack_w_kernel<<<dim3(16, 16, 4), 256, 0, stream>>>(Wq, Wk, Wv, Wo, Wt);

    gemm_qkv_kernel<<<dim3(3072 / 128, T_ / 256), 512, 0, stream>>>(
        hsb, Wt, bqkv, mask, cosT, sinT, qb, kb, vb);

    kv_part_kernel<<<dim3(B_ * NH, NCH), 256, 0, stream>>>(
        kb, vb, kvpart, kspart);
    reduce_part_kernel<<<(262144 + 4096 + 255) / 256, 256, 0, stream>>>(
        kvpart, kspart, kvb, ksum);

    combine_kernel<<<dim3(B_ * NH, S_ / 256), 256, 0, stream>>>(
        qb, kvb, ksum, gbuf, coeff, cmb);

    gemm_out_kernel<<<dim3(H_ / 128, T_ / 256), 512, 0, stream>>>(
        cmb, WoT, bo, out, H_);
}

// Round 7
// 249.657 us; speedup vs baseline: 1.0003x; 1.0003x over previous
//
#include <hip/hip_runtime.h>
#include <math.h>

#define B_   4
#define S_   2048
#define H_   1024
#define NH   16
#define HD   64
#define T_   (B_ * S_)       // 8192 tokens
#define NCH  16              // kv S-chunks

typedef unsigned short u16;
typedef __bf16 bf16x8 __attribute__((ext_vector_type(8)));
typedef float  f32x4  __attribute__((ext_vector_type(4)));

// ---------------------------------------------------------------------------
__device__ __forceinline__ float elu_k(float x) {
    return (x > 0.f ? x : (expf(x) - 1.f)) + 1.000001f;
}

__device__ __forceinline__ u16 f2bf(float x) {
    union { float f; unsigned int u; } v; v.f = x;
    unsigned int r = v.u + 0x7FFFu + ((v.u >> 16) & 1u);
    return (u16)(r >> 16);
}

__device__ __forceinline__ float bfl(unsigned int u) {
    union { unsigned int u; float f; } v; v.u = u << 16; return v.f;
}
__device__ __forceinline__ float bfh(unsigned int u) {
    union { unsigned int u; float f; } v; v.u = u & 0xFFFF0000u; return v.f;
}

// async global->LDS, 16 B/lane; LDS side uses lane0's base + lane*16,
// global side is per-lane.
__device__ __forceinline__ void async_load16(const u16* g, u16* l) {
    __builtin_amdgcn_global_load_lds(
        (const __attribute__((address_space(1))) void*)g,
        (__attribute__((address_space(3))) void*)l,
        16, 0, 0);
}

// ---------------------------------------------------------------------------
// prep: rope tables + packed bias + coeff, one launch.
__global__ __launch_bounds__(256) void prep_kernel(
    const float* __restrict__ decay, const float* __restrict__ gate,
    float* __restrict__ coeff, float* __restrict__ cosT,
    float* __restrict__ sinT, const float* __restrict__ bq,
    const float* __restrict__ bk, const float* __restrict__ bv,
    float* __restrict__ bqkv) {
    int idx = blockIdx.x * 256 + threadIdx.x;
    if (idx < S_ * 32) {
        int s = idx >> 5, i = idx & 31;
        float inv = powf(10000.f, -(2.f * (float)i) / 64.f);
        float f = (float)s * inv;
        cosT[idx] = cosf(f);
        sinT[idx] = sinf(f);
    } else if (idx < S_ * 32 + 3072) {
        int i = idx - S_ * 32;
        bqkv[i] = (i < 1024) ? bq[i] : (i < 2048) ? bk[i - 1024] : bv[i - 2048];
    } else if (idx == S_ * 32 + 3072) {
        float g0 = gate[0], g1 = gate[1], g2 = gate[2];
        float mx = fmaxf(g0, fmaxf(g1, g2));
        float e0 = expf(g0 - mx), e1 = expf(g1 - mx), e2 = expf(g2 - mx);
        float inv = 1.f / (e0 + e1 + e2);
        float es[3] = {e0, e1, e2};
        float c = 0.f;
        for (int m = 0; m < 3; m++) {
            float ds = 1.f / (1.f + expf(-decay[m]));
            c += es[m] * inv * (1.f - ds);
        }
        *coeff = c;
    }
}

// ---------------------------------------------------------------------------
// Fused hs->bf16 convert + gate gemv. One block per token.
__global__ __launch_bounds__(256) void cvt_gate_kernel(
    const float* __restrict__ hs, const float* __restrict__ Wg,
    const float* __restrict__ bg, u16* __restrict__ hsb,
    float* __restrict__ gbuf) {
    int t = blockIdx.x;
    int i = threadIdx.x;
    float4 f = ((const float4*)(hs + (size_t)t * H_))[i];
    float4 w = ((const float4*)Wg)[i];
    ushort4 u;
    u.x = f2bf(f.x); u.y = f2bf(f.y); u.z = f2bf(f.z); u.w = f2bf(f.w);
    ((ushort4*)(hsb + (size_t)t * H_))[i] = u;
    float s = f.x * w.x + f.y * w.y + f.z * w.z + f.w * w.w;
#pragma unroll
    for (int off = 32; off > 0; off >>= 1) s += __shfl_down(s, off);
    __shared__ float wsum[4];
    if ((i & 63) == 0) wsum[i >> 6] = s;
    __syncthreads();
    if (i == 0) {
        float tot = wsum[0] + wsum[1] + wsum[2] + wsum[3];
        gbuf[t] = 1.f / (1.f + expf(-(tot + bg[0])));
    }
}

// ---------------------------------------------------------------------------
// Transpose+convert weights: Wt[w*1024 + n][k] = bf16(W_w[k][n])
__global__ __launch_bounds__(256) void pack_w_kernel(
    const float* __restrict__ Wq, const float* __restrict__ Wk,
    const float* __restrict__ Wv, const float* __restrict__ Wo,
    u16* __restrict__ Wt) {
    __shared__ u16 tile[64][65];
    const float* W = (blockIdx.z == 0) ? Wq :
                     (blockIdx.z == 1) ? Wk :
                     (blockIdx.z == 2) ? Wv : Wo;
    int nt = blockIdx.x * 64, kt = blockIdx.y * 64;
    int tid = threadIdx.x;
#pragma unroll
    for (int it = 0; it < 16; it++) {
        int i = it * 256 + tid;
        int kr = i >> 6, nc = i & 63;
        tile[kr][nc] = f2bf(W[(size_t)(kt + kr) * H_ + nt + nc]);
    }
    __syncthreads();
    size_t wbase = (size_t)blockIdx.z * H_;
#pragma unroll
    for (int it = 0; it < 16; it++) {
        int i = it * 256 + tid;
        int nr = i >> 6, kc = i & 63;
        Wt[(wbase + nt + nr) * H_ + kt + kc] = tile[kc][nr];
    }
}

// ---------------------------------------------------------------------------
// GEMM core v6: R5 geometry + read-ahead software pipeline + TRIPLE buffer.
// BM=256, BN=128, BK=64, 512 thr = 8 waves (4M x 2N), per-wave C = 64x64.
// LDS 144 KiB: A bufs [3][256][64] at u16 off {0,16384,32768};
//              B bufs [3][128][64] at u16 off {49152,57344,65536}.
// T2 chunk-XOR swizzle unchanged (0 conflicts measured R1-R5).
//
// Read-ahead schedule (every lgkm wait pre-covered by an MFMA cluster):
//   tile n:  1. issue G0(n) (8 ds_read, buf n%3)     <- flies under M1
//            2. lgkm(8) -> M1(n-1) (kk1 of prev)      <- covers G0(n)
//            3. B_a  (all waves' reads of buf (n-1)%3 drained at step 2)
//            4. STAGE(n+2) -> buf (n+2)%3 (== (n-1)%3, just freed)
//               issue G1(n) (8 ds_read, buf n%3)
//            5. lgkm(8) -> M0(n) (kk0)                <- covers G1(n)
//            6. vmcnt(6) [stage(n+1) landed; stage(n+2) stays in flight]; B_b
//   MFMA order kk0(n),kk1(n),kk0(n+1),... identical to R5 -> bit-identical.
//   Stage(n+2): issue(tile n) -> wait(tile n+1 end) = ~1.5 tiles > HBM 900cy.
// Race ledger:
//  - writers in any barrier window touch only buf (n+2)%3; readers touch only
//    buf n%3 (windows B_b->B_a: G0 reads; B_a->B_b: G1 reads). (n+2)%3 != n%3.
//  - in-flight stage(n+2) crosses B_b(n)..B_b(n+1); readers of buf (n+2)%3
//    first appear after B_b(n+1), gated by vmcnt(6) at tile n+1 step 6.
//  - per-wave: step 2's lgkm(8) drains G1(n-1) (oldest 8 of 16) before the
//    stage that overwrites that buffer (step 4, after B_a).
//  - n=14: no stage(16) -> vmcnt(0) drains stage(15). n=15: no B_b; M1(15)
//    runs in epilogue after lgkm(0).
// Barrier parity: B_a unconditional, B_b for n<=14 — uniform across waves.

#define STAGE6(AST, BST)                                                      \
    {                                                                         \
        async_load16(pa0, &sAB[(AST) + wid * 2048 + lane * 8]);               \
        async_load16(pa1, &sAB[(AST) + wid * 2048 + 512 + lane * 8]);         \
        async_load16(pa2, &sAB[(AST) + wid * 2048 + 1024 + lane * 8]);        \
        async_load16(pa3, &sAB[(AST) + wid * 2048 + 1536 + lane * 8]);        \
        async_load16(pb0, &sAB[(BST) + wid * 1024 + lane * 8]);               \
        async_load16(pb1, &sAB[(BST) + wid * 1024 + 512 + lane * 8]);         \
        pa0 += 64; pa1 += 64; pa2 += 64; pa3 += 64; pb0 += 64; pb1 += 64;     \
    }

#define MFMA16(AV, BV)                                                        \
    __builtin_amdgcn_s_setprio(1);                                            \
    _Pragma("unroll")                                                         \
    for (int mi = 0; mi < 4; mi++)                                            \
        _Pragma("unroll")                                                     \
        for (int nj = 0; nj < 4; nj++)                                        \
            acc[mi][nj] = __builtin_amdgcn_mfma_f32_16x16x32_bf16(            \
                AV[mi], BV[nj], acc[mi][nj], 0, 0, 0);                        \
    __builtin_amdgcn_s_setprio(0);

// buffer offsets are pure arithmetic (fold to immediates under full unroll)
#define KLOOP(A_, Bt_)                                                        \
    const u16* pa0 = A_ + (size_t)(bm + wid * 32 +  0 + ln8) * 1024 + scs8;   \
    const u16* pa1 = A_ + (size_t)(bm + wid * 32 +  8 + ln8) * 1024 + scs8;   \
    const u16* pa2 = A_ + (size_t)(bm + wid * 32 + 16 + ln8) * 1024 + scs8;   \
    const u16* pa3 = A_ + (size_t)(bm + wid * 32 + 24 + ln8) * 1024 + scs8;   \
    const u16* pb0 = Bt_ + (size_t)(bn + wid * 16 +  0 + ln8) * 1024 + scs8;  \
    const u16* pb1 = Bt_ + (size_t)(bn + wid * 16 +  8 + ln8) * 1024 + scs8;  \
    bf16x8 a0[4], b0[4], a1[4], b1[4];                                        \
    STAGE6(0, 49152)                        /* stage tile 0 -> buf0 */        \
    STAGE6(16384, 57344)                    /* stage tile 1 -> buf1 */        \
    asm volatile("s_waitcnt vmcnt(6)" ::: "memory");  /* tile0 landed */      \
    __builtin_amdgcn_s_barrier();                                             \
    _Pragma("unroll")                                                         \
    for (int n = 0; n < 16; ++n) {                                            \
        const int rdA = (n % 3) * 16384;                                      \
        const int rdB = 49152 + (n % 3) * 8192;                               \
        const int stA = ((n + 2) % 3) * 16384;                                \
        const int stB = 49152 + ((n + 2) % 3) * 8192;                         \
        const u16* Ab = &sAB[rdA + (wr * 64 + l15) * 64];                     \
        const u16* Bb = &sAB[rdB + (wc * 64 + l15) * 64];                     \
        /* 1: issue G0(n) */                                                  \
        _Pragma("unroll")                                                     \
        for (int mi = 0; mi < 4; mi++)                                        \
            a0[mi] = *(const bf16x8*)&Ab[mi * 1024 + sw0];                    \
        _Pragma("unroll")                                                     \
        for (int nj = 0; nj < 4; nj++)                                        \
            b0[nj] = *(const bf16x8*)&Bb[nj * 1024 + sw0];                    \
        __builtin_amdgcn_sched_barrier(0);                                    \
        /* 2: M1(n-1) under G0(n) */                                          \
        if (n > 0) {                                                          \
            asm volatile("s_waitcnt lgkmcnt(8)" ::: "memory");                \
            __builtin_amdgcn_sched_barrier(0);                                \
            MFMA16(a1, b1)                                                    \
            __builtin_amdgcn_sched_barrier(0);                                \
        }                                                                     \
        /* 3: B_a — buf (n-1)%3 fully read by all waves */                    \
        asm volatile("" ::: "memory");                                        \
        __builtin_amdgcn_s_barrier();                                         \
        /* 4: stage(n+2) into freed buffer; issue G1(n) */                    \
        if (n + 2 < 16) STAGE6(stA, stB)                                      \
        _Pragma("unroll")                                                     \
        for (int mi = 0; mi < 4; mi++)                                        \
            a1[mi] = *(const bf16x8*)&Ab[mi * 1024 + sw1];                    \
        _Pragma("unroll")                                                     \
        for (int nj = 0; nj < 4; nj++)                                        \
            b1[nj] = *(const bf16x8*)&Bb[nj * 1024 + sw1];                    \
        __builtin_amdgcn_sched_barrier(0);                                    \
        /* 5: M0(n) under G1(n) */                                            \
        asm volatile("s_waitcnt lgkmcnt(8)" ::: "memory");                    \
        __builtin_amdgcn_sched_barrier(0);                                    \
        MFMA16(a0, b0)                                                        \
        __builtin_amdgcn_sched_barrier(0);                                    \
        /* 6: counted vmcnt + B_b */                                          \
        if (n < 14) {                                                         \
            asm volatile("s_waitcnt vmcnt(6)" ::: "memory");                  \
            asm volatile("" ::: "memory");                                    \
            __builtin_amdgcn_s_barrier();                                     \
        } else if (n == 14) {                                                 \
            asm volatile("s_waitcnt vmcnt(0)" ::: "memory");                  \
            asm volatile("" ::: "memory");                                    \
            __builtin_amdgcn_s_barrier();                                     \
        }                                                                     \
    }                                                                         \
    /* epilogue of pipeline: M1(15) */                                        \
    asm volatile("s_waitcnt lgkmcnt(0)" ::: "memory");                        \
    __builtin_amdgcn_sched_barrier(0);                                        \
    MFMA16(a1, b1)

// bijective XCD swizzle (nwg % 8 == 0 for both GEMM grids): each XCD gets a
// contiguous chunk of row-major block ids -> its A-row-panels stay in its L2.
#define XCD_SWIZZLE(BM_, BN_)                                                 \
    const int nwg = gridDim.x * gridDim.y;                                    \
    int orig = blockIdx.y * gridDim.x + blockIdx.x;                           \
    int wg = (orig & 7) * (nwg >> 3) + (orig >> 3);                           \
    const int bm = (wg / gridDim.x) * (BM_), bn = (wg % gridDim.x) * (BN_);

// ---------------------------------------------------------------------------
// QKV GEMM with fused rope+elu+mask epilogue -> bf16 head-major qb/kb/vb.
// grid (24, 32) = 768 blocks = 3.0 perfect rounds at 1 block/CU.
__global__ __launch_bounds__(512, 2) void gemm_qkv_kernel(
    const u16* __restrict__ A, const u16* __restrict__ Bt,
    const float* __restrict__ bias, const float* __restrict__ mask,
    const float* __restrict__ cosT, const float* __restrict__ sinT,
    u16* __restrict__ qb, u16* __restrict__ kb, u16* __restrict__ vb) {
    __shared__ u16 sAB[73728];                 // 144 KiB, triple-buffered
    const int tid  = threadIdx.x;
    const int wid  = tid >> 6, lane = tid & 63;
    const int wr = wid >> 1, wc = wid & 1;
    const int l15 = lane & 15, quad = lane >> 4;
    const int ln8 = lane >> 3;
    const int scs8 = ((lane & 7) ^ ln8) * 8;
    const int sw0 = (quad ^ (l15 & 7)) * 8;
    const int sw1 = ((4 + quad) ^ (l15 & 7)) * 8;
    XCD_SWIZZLE(256, 128)

    f32x4 acc[4][4];
#pragma unroll
    for (int i = 0; i < 4; i++)
#pragma unroll
        for (int j = 0; j < 4; j++) acc[i][j] = {0.f, 0.f, 0.f, 0.f};

    KLOOP(A, Bt)

    // ---- fused epilogue
    const int colbase = bn + wc * 64;          // multiple of 64
    const int region  = colbase >> 10;         // 0=q 1=k 2=v
    const int nh      = (colbase & 1023) >> 6;
    float bc[4];
#pragma unroll
    for (int nj = 0; nj < 4; nj++) bc[nj] = bias[colbase + nj * 16 + l15];
    u16* outp = (region == 0) ? qb : (region == 1) ? kb : vb;

#pragma unroll
    for (int mi = 0; mi < 4; mi++) {
#pragma unroll
        for (int r = 0; r < 4; r++) {
            int row = bm + wr * 64 + mi * 16 + quad * 4 + r;
            int b = row >> 11, s = row & (S_ - 1);
            size_t obase = ((size_t)(b * 16 + nh) * S_ + s) * 64;
            if (region < 2) {
                float mfac = (region == 0) ? 0.125f : mask[row];
#pragma unroll
                for (int p = 0; p < 2; p++) {
                    int d1 = p * 16 + l15;
                    float c  = cosT[s * 32 + d1];
                    float sn = sinT[s * 32 + d1];
                    float x1 = acc[mi][p][r]     + bc[p];
                    float x2 = acc[mi][p + 2][r] + bc[p + 2];
                    float r1 = x1 * c - x2 * sn;
                    float r2 = x2 * c + x1 * sn;
                    outp[obase + d1]      = f2bf(elu_k(r1) * mfac);
                    outp[obase + d1 + 32] = f2bf(elu_k(r2) * mfac);
                }
            } else {
                float mfac = mask[row];
#pragma unroll
                for (int nj = 0; nj < 4; nj++)
                    outp[obase + nj * 16 + l15] =
                        f2bf((acc[mi][nj][r] + bc[nj]) * mfac);
            }
        }
    }
}

// ---------------------------------------------------------------------------
// Output projection GEMM: C fp32 = A @ Bt^T + bias.
// grid (8, 32) = 256 blocks = 1.0 perfect round at 1 block/CU.
__global__ __launch_bounds__(512, 2) void gemm_out_kernel(
    const u16* __restrict__ A, const u16* __restrict__ Bt,
    const float* __restrict__ bias, float* __restrict__ C, int N) {
    __shared__ u16 sAB[73728];                 // 144 KiB, triple-buffered
    const int tid  = threadIdx.x;
    const int wid  = tid >> 6, lane = tid & 63;
    const int wr = wid >> 1, wc = wid & 1;
    const int l15 = lane & 15, quad = lane >> 4;
    const int ln8 = lane >> 3;
    const int scs8 = ((lane & 7) ^ ln8) * 8;
    const int sw0 = (quad ^ (l15 & 7)) * 8;
    const int sw1 = ((4 + quad) ^ (l15 & 7)) * 8;
    XCD_SWIZZLE(256, 128)

    f32x4 acc[4][4];
#pragma unroll
    for (int i = 0; i < 4; i++)
#pragma unroll
        for (int j = 0; j < 4; j++) acc[i][j] = {0.f, 0.f, 0.f, 0.f};

    KLOOP(A, Bt)

#pragma unroll
    for (int mi = 0; mi < 4; mi++) {
#pragma unroll
        for (int nj = 0; nj < 4; nj++) {
            int col = bn + wc * 64 + nj * 16 + l15;
            float bcol = bias[col];
#pragma unroll
            for (int r = 0; r < 4; r++) {
                int row = bm + wr * 64 + mi * 16 + quad * 4 + r;
                C[(size_t)row * N + col] = acc[mi][nj][r] + bcol;
            }
        }
    }
}

// ---------------------------------------------------------------------------
// kv partials from bf16 head-major k,v: grid (64 bn, NCH).
__global__ __launch_bounds__(256) void kv_part_kernel(
    const u16* __restrict__ kb, const u16* __restrict__ vb,
    float* __restrict__ kvpart, float* __restrict__ kspart) {
    int bn = blockIdx.x;
    const int rows = S_ / NCH;              // 128
    int s0 = blockIdx.y * rows;
    int tid = threadIdx.x;
    int ti = tid >> 4, tj = tid & 15;
    __shared__ float ks[16][64], vs[16][64];
    float acc[4][4] = {};
    float ksacc = 0.f;
    const u16* kbase = kb + (size_t)bn * (S_ * 64) + (size_t)s0 * 64;
    const u16* vbase = vb + (size_t)bn * (S_ * 64) + (size_t)s0 * 64;
    for (int ss = 0; ss < rows; ss += 16) {
        {
            int half = tid >> 7;
            int c = tid & 127;
            int rr = c >> 3, col = (c & 7) * 8;
            const u16* src = (half ? vbase : kbase) + (size_t)(ss + rr) * 64 + col;
            uint4 raw = *(const uint4*)src;
            float* dst = half ? &vs[rr][col] : &ks[rr][col];
            dst[0] = bfl(raw.x); dst[1] = bfh(raw.x);
            dst[2] = bfl(raw.y); dst[3] = bfh(raw.y);
            dst[4] = bfl(raw.z); dst[5] = bfh(raw.z);
            dst[6] = bfl(raw.w); dst[7] = bfh(raw.w);
        }
        __syncthreads();
#pragma unroll
        for (int r = 0; r < 16; r++) {
            float a[4], bb[4];
#pragma unroll
            for (int i = 0; i < 4; i++) a[i] = ks[r][ti * 4 + i];
#pragma unroll
            for (int j = 0; j < 4; j++) bb[j] = vs[r][tj * 4 + j];
#pragma unroll
            for (int i = 0; i < 4; i++)
#pragma unroll
                for (int j = 0; j < 4; j++)
                    acc[i][j] = fmaf(a[i], bb[j], acc[i][j]);
        }
        if (tid < 64) {
#pragma unroll
            for (int r = 0; r < 16; r++) ksacc += ks[r][tid];
        }
        __syncthreads();
    }
    size_t obase = ((size_t)blockIdx.y * 64 + bn) * 4096;
#pragma unroll
    for (int i = 0; i < 4; i++)
#pragma unroll
        for (int j = 0; j < 4; j++)
            kvpart[obase + (size_t)(ti * 4 + i) * 64 + tj * 4 + j] = acc[i][j];
    if (tid < 64)
        kspart[((size_t)blockIdx.y * 64 + bn) * 64 + tid] = ksacc;
}

// sum NCH partials for kv (262144) and ksum (4096) in one launch
__global__ __launch_bounds__(256) void reduce_part_kernel(
    const float* __restrict__ kvpart, const float* __restrict__ kspart,
    float* __restrict__ kvb, float* __restrict__ ksum) {
    int i = blockIdx.x * 256 + threadIdx.x;
    if (i < 262144) {
        float s = 0.f;
#pragma unroll
        for (int c = 0; c < NCH; c++) s += kvpart[(size_t)c * 262144 + i];
        kvb[i] = s;
    } else if (i < 262144 + 4096) {
        int j = i - 262144;
        float s = 0.f;
#pragma unroll
        for (int c = 0; c < NCH; c++) s += kspart[(size_t)c * 4096 + j];
        ksum[j] = s;
    }
}

// ---------------------------------------------------------------------------
// MFMA combine: per (b,n), num = Q[256x64] @ kv[64x64], den via ksum column.
__global__ __launch_bounds__(256) void combine_kernel(
    const u16* __restrict__ qb, const float* __restrict__ kvb,
    const float* __restrict__ ksum, const float* __restrict__ g,
    const float* __restrict__ coeffp, u16* __restrict__ cmb) {
    int bn = blockIdx.x;
    int b = bn >> 4, n = bn & 15;
    __shared__ u16 qs[256 * 72];
    __shared__ u16 kvT[64 * 72];
    __shared__ u16 ksl[128];
    int tid = threadIdx.x;
    int s0 = blockIdx.y * 256;

    const u16* qsrc = qb + (size_t)bn * (S_ * 64) + (size_t)s0 * 64;
    for (int c = tid; c < 2048; c += 256) {
        int t = c >> 3, k8 = (c & 7) * 8;
        float4 tmp = *(const float4*)(qsrc + (size_t)c * 8);
        *(float4*)&qs[t * 72 + k8] = tmp;
    }
    for (int c = tid; c < 1024; c += 256) {
        int i = c >> 4, d4 = (c & 15) * 4;
        float4 kvv = *(const float4*)&kvb[(size_t)bn * 4096 + i * 64 + d4];
        kvT[(d4 + 0) * 72 + i] = f2bf(kvv.x);
        kvT[(d4 + 1) * 72 + i] = f2bf(kvv.y);
        kvT[(d4 + 2) * 72 + i] = f2bf(kvv.z);
        kvT[(d4 + 3) * 72 + i] = f2bf(kvv.w);
    }
    if (tid < 64)        ksl[tid] = f2bf(ksum[bn * 64 + tid]);
    else if (tid < 128)  ksl[tid] = 0;
    __syncthreads();

    int wave = tid >> 6, lane = tid & 63;
    int l15 = lane & 15, quad = lane >> 4;
    int wt = wave * 64;

    int ko0 = (l15 == 0) ? quad * 8      : 64;
    int ko1 = (l15 == 0) ? 32 + quad * 8 : 64;
    bf16x8 ksf0 = *(const bf16x8*)&ksl[ko0];
    bf16x8 ksf1 = *(const bf16x8*)&ksl[ko1];

    bf16x8 bfr0[4], bfr1[4];
#pragma unroll
    for (int nj = 0; nj < 4; nj++) {
        bfr0[nj] = *(const bf16x8*)&kvT[(nj * 16 + l15) * 72 + quad * 8];
        bfr1[nj] = *(const bf16x8*)&kvT[(nj * 16 + l15) * 72 + 32 + quad * 8];
    }

    f32x4 acc[4][4], dacc[4];
#pragma unroll
    for (int i = 0; i < 4; i++) {
        dacc[i] = {0.f, 0.f, 0.f, 0.f};
#pragma unroll
        for (int j = 0; j < 4; j++) acc[i][j] = {0.f, 0.f, 0.f, 0.f};
    }

#pragma unroll
    for (int mi = 0; mi < 4; mi++) {
        bf16x8 a0 = *(const bf16x8*)&qs[(wt + mi * 16 + l15) * 72 + quad * 8];
        bf16x8 a1 = *(const bf16x8*)&qs[(wt + mi * 16 + l15) * 72 + 32 + quad * 8];
        dacc[mi] = __builtin_amdgcn_mfma_f32_16x16x32_bf16(a0, ksf0, dacc[mi], 0, 0, 0);
        dacc[mi] = __builtin_amdgcn_mfma_f32_16x16x32_bf16(a1, ksf1, dacc[mi], 0, 0, 0);
#pragma unroll
        for (int nj = 0; nj < 4; nj++) {
            acc[mi][nj] = __builtin_amdgcn_mfma_f32_16x16x32_bf16(
                a0, bfr0[nj], acc[mi][nj], 0, 0, 0);
            acc[mi][nj] = __builtin_amdgcn_mfma_f32_16x16x32_bf16(
                a1, bfr1[nj], acc[mi][nj], 0, 0, 0);
        }
    }

    float coeff = *coeffp;
#pragma unroll
    for (int mi = 0; mi < 4; mi++) {
#pragma unroll
        for (int r = 0; r < 4; r++) {
            int s = s0 + wt + mi * 16 + quad * 4 + r;
            int t = b * S_ + s;
            float den = __shfl(dacc[mi][r], lane & 48) + 1e-6f;
            float gv = g[t];
            float w1 = gv / den + (1.f - gv) * coeff;
#pragma unroll
            for (int nj = 0; nj < 4; nj++) {
                int d = nj * 16 + l15;
                cmb[(size_t)t * H_ + n * 64 + d] = f2bf(acc[mi][nj][r] * w1);
            }
        }
    }
}

// ---------------------------------------------------------------------------
extern "C" void kernel_launch(void* const* d_in, const int* in_sizes, int n_in,
                              void* d_out, int out_size, void* d_ws, size_t ws_size,
                              hipStream_t stream) {
    const float* hs    = (const float*)d_in[0];
    const float* mask  = (const float*)d_in[1];
    const float* Wq    = (const float*)d_in[2];
    const float* bq    = (const float*)d_in[3];
    const float* Wk    = (const float*)d_in[4];
    const float* bk    = (const float*)d_in[5];
    const float* Wv    = (const float*)d_in[6];
    const float* bv    = (const float*)d_in[7];
    const float* Wo    = (const float*)d_in[8];
    const float* bo    = (const float*)d_in[9];
    const float* Wg    = (const float*)d_in[10];
    const float* bg    = (const float*)d_in[11];
    const float* decay = (const float*)d_in[12];
    const float* gate  = (const float*)d_in[13];
    float* out = (float*)d_out;

    // ---- workspace layout
    float* ws     = (float*)d_ws;
    float* kvb    = ws;                         // 262144
    float* ksum   = kvb + 262144;               // 4096
    float* gbuf   = ksum + 4096;                // 8192
    float* coeff  = gbuf + 8192;                // 64
    float* cosT   = coeff + 64;                 // 65536
    float* sinT   = cosT + 65536;               // 65536
    float* bqkv   = sinT + 65536;               // 3072 (+pad to 4096)
    float* kspart = bqkv + 4096;                // NCH*4096 = 65536
    float* kvpart = kspart + 65536;             // NCH*262144 = 4194304
    u16*   hsb    = (u16*)(kvpart + 4194304);   // T*1024
    u16*   Wt     = hsb + (size_t)T_ * H_;      // 4096*1024
    u16*   WoT    = Wt + (size_t)3072 * H_;
    u16*   qb     = Wt + (size_t)4096 * H_;     // T*1024 head-major
    u16*   kb     = qb + (size_t)T_ * H_;
    u16*   vb     = kb + (size_t)T_ * H_;
    u16*   cmb    = vb + (size_t)T_ * H_;

    prep_kernel<<<(S_ * 32 + 3072 + 256) / 256 + 1, 256, 0, stream>>>(
        decay, gate, coeff, cosT, sinT, bq, bk, bv, bqkv);
    cvt_gate_kernel<<<T_, 256, 0, stream>>>(hs, Wg, bg, hsb, gbuf);
    pack_w_kernel<<<dim3(16, 16, 4), 256, 0, stream>>>(Wq, Wk, Wv, Wo, Wt);

    gemm_qkv_kernel<<<dim3(3072 / 128, T_ / 256), 512, 0, stream>>>(
        hsb, Wt, bqkv, mask, cosT, sinT, qb, kb, vb);

    kv_part_kernel<<<dim3(B_ * NH, NCH), 256, 0, stream>>>(
        kb, vb, kvpart, kspart);
    reduce_part_kernel<<<(262144 + 4096 + 255) / 256, 256, 0, stream>>>(
        kvpart, kspart, kvb, ksum);

    combine_kernel<<<dim3(B_ * NH, S_ / 256), 256, 0, stream>>>(
        qb, kvb, ksum, gbuf, coeff, cmb);

    gemm_out_kernel<<<dim3(H_ / 128, T_ / 256), 512, 0, stream>>>(
        cmb, WoT, bo, out, H_);
}

// Round 8
// 240.277 us; speedup vs baseline: 1.0394x; 1.0390x over previous
//
#include <hip/hip_runtime.h>
#include <math.h>

#define B_   4
#define S_   2048
#define H_   1024
#define NH   16
#define HD   64
#define T_   (B_ * S_)       // 8192 tokens
#define NCH  16              // kv S-chunks

typedef unsigned short u16;
typedef __bf16 bf16x8 __attribute__((ext_vector_type(8)));
typedef float  f32x4  __attribute__((ext_vector_type(4)));

// ---------------------------------------------------------------------------
__device__ __forceinline__ float elu_k(float x) {
    return (x > 0.f ? x : (expf(x) - 1.f)) + 1.000001f;
}

__device__ __forceinline__ u16 f2bf(float x) {
    union { float f; unsigned int u; } v; v.f = x;
    unsigned int r = v.u + 0x7FFFu + ((v.u >> 16) & 1u);
    return (u16)(r >> 16);
}

__device__ __forceinline__ float bfl(unsigned int u) {
    union { unsigned int u; float f; } v; v.u = u << 16; return v.f;
}
__device__ __forceinline__ float bfh(unsigned int u) {
    union { unsigned int u; float f; } v; v.u = u & 0xFFFF0000u; return v.f;
}

// async global->LDS, 16 B/lane; LDS side uses lane0's base + lane*16,
// global side is per-lane.
__device__ __forceinline__ void async_load16(const u16* g, u16* l) {
    __builtin_amdgcn_global_load_lds(
        (const __attribute__((address_space(1))) void*)g,
        (__attribute__((address_space(3))) void*)l,
        16, 0, 0);
}

// ---------------------------------------------------------------------------
// Merged prologue: cvt_gate (blocks 0..8191) | pack_w (8192..9215) |
// prep (9216..9485).  The three sections are fully independent (disjoint
// reads/writes), merged to overlap their memory streams and save 2 launches.
__global__ __launch_bounds__(256) void pre_kernel(
    const float* __restrict__ hs, const float* __restrict__ Wg,
    const float* __restrict__ bg, const float* __restrict__ Wq,
    const float* __restrict__ Wk, const float* __restrict__ Wv,
    const float* __restrict__ Wo, const float* __restrict__ decay,
    const float* __restrict__ gate, const float* __restrict__ bq,
    const float* __restrict__ bk, const float* __restrict__ bv,
    u16* __restrict__ hsb, float* __restrict__ gbuf, u16* __restrict__ Wt,
    float* __restrict__ coeff, float* __restrict__ cosT,
    float* __restrict__ sinT, float* __restrict__ bqkv) {
    __shared__ u16 tile[64][65];
    __shared__ float wsum[4];
    const int blk = blockIdx.x;
    const int tid = threadIdx.x;

    if (blk < T_) {
        // ---- cvt_gate: hs->bf16 + gate gemv, one block per token
        int t = blk;
        float4 f = ((const float4*)(hs + (size_t)t * H_))[tid];
        float4 w = ((const float4*)Wg)[tid];
        ushort4 u;
        u.x = f2bf(f.x); u.y = f2bf(f.y); u.z = f2bf(f.z); u.w = f2bf(f.w);
        ((ushort4*)(hsb + (size_t)t * H_))[tid] = u;
        float s = f.x * w.x + f.y * w.y + f.z * w.z + f.w * w.w;
#pragma unroll
        for (int off = 32; off > 0; off >>= 1) s += __shfl_down(s, off);
        if ((tid & 63) == 0) wsum[tid >> 6] = s;
        __syncthreads();
        if (tid == 0) {
            float tot = wsum[0] + wsum[1] + wsum[2] + wsum[3];
            gbuf[t] = 1.f / (1.f + expf(-(tot + bg[0])));
        }
    } else if (blk < T_ + 1024) {
        // ---- pack_w: Wt[w*1024 + n][k] = bf16(W_w[k][n])
        int idx = blk - T_;
        int wsel = idx >> 8, rem = idx & 255;
        int nt = (rem & 15) * 64, kt = (rem >> 4) * 64;
        const float* W = (wsel == 0) ? Wq : (wsel == 1) ? Wk :
                         (wsel == 2) ? Wv : Wo;
#pragma unroll
        for (int it = 0; it < 16; it++) {
            int i = it * 256 + tid;
            int kr = i >> 6, nc = i & 63;
            tile[kr][nc] = f2bf(W[(size_t)(kt + kr) * H_ + nt + nc]);
        }
        __syncthreads();
        size_t wbase = (size_t)wsel * H_;
#pragma unroll
        for (int it = 0; it < 16; it++) {
            int i = it * 256 + tid;
            int nr = i >> 6, kc = i & 63;
            Wt[(wbase + nt + nr) * H_ + kt + kc] = tile[kc][nr];
        }
    } else {
        // ---- prep: rope tables + packed bias + coeff
        int idx = (blk - (T_ + 1024)) * 256 + tid;
        if (idx < S_ * 32) {
            int s = idx >> 5, i = idx & 31;
            float inv = powf(10000.f, -(2.f * (float)i) / 64.f);
            float f = (float)s * inv;
            cosT[idx] = cosf(f);
            sinT[idx] = sinf(f);
        } else if (idx < S_ * 32 + 3072) {
            int i = idx - S_ * 32;
            bqkv[i] = (i < 1024) ? bq[i] : (i < 2048) ? bk[i - 1024]
                                                      : bv[i - 2048];
        } else if (idx == S_ * 32 + 3072) {
            float g0 = gate[0], g1 = gate[1], g2 = gate[2];
            float mx = fmaxf(g0, fmaxf(g1, g2));
            float e0 = expf(g0 - mx), e1 = expf(g1 - mx), e2 = expf(g2 - mx);
            float inv = 1.f / (e0 + e1 + e2);
            float es[3] = {e0, e1, e2};
            float c = 0.f;
            for (int m = 0; m < 3; m++) {
                float ds = 1.f / (1.f + expf(-decay[m]));
                c += es[m] * inv * (1.f - ds);
            }
            *coeff = c;
        }
    }
}

// ---------------------------------------------------------------------------
// GEMM core v6 (qkv): BM=256, BN=128, BK=64, 8 waves, triple-buffered LDS
// with read-ahead pipeline.  Measured R7: 76.8 us, 0 bank conflicts.
// Full schedule + race ledger: see R5/R7 notes; unchanged here.

#define STAGE6(AST, BST)                                                      \
    {                                                                         \
        async_load16(pa0, &sAB[(AST) + wid * 2048 + lane * 8]);               \
        async_load16(pa1, &sAB[(AST) + wid * 2048 + 512 + lane * 8]);         \
        async_load16(pa2, &sAB[(AST) + wid * 2048 + 1024 + lane * 8]);        \
        async_load16(pa3, &sAB[(AST) + wid * 2048 + 1536 + lane * 8]);        \
        async_load16(pb0, &sAB[(BST) + wid * 1024 + lane * 8]);               \
        async_load16(pb1, &sAB[(BST) + wid * 1024 + 512 + lane * 8]);         \
        pa0 += 64; pa1 += 64; pa2 += 64; pa3 += 64; pb0 += 64; pb1 += 64;     \
    }

#define MFMA16(AV, BV)                                                        \
    __builtin_amdgcn_s_setprio(1);                                            \
    _Pragma("unroll")                                                         \
    for (int mi = 0; mi < 4; mi++)                                            \
        _Pragma("unroll")                                                     \
        for (int nj = 0; nj < 4; nj++)                                        \
            acc[mi][nj] = __builtin_amdgcn_mfma_f32_16x16x32_bf16(            \
                AV[mi], BV[nj], acc[mi][nj], 0, 0, 0);                        \
    __builtin_amdgcn_s_setprio(0);

#define KLOOP(A_, Bt_)                                                        \
    const u16* pa0 = A_ + (size_t)(bm + wid * 32 +  0 + ln8) * 1024 + scs8;   \
    const u16* pa1 = A_ + (size_t)(bm + wid * 32 +  8 + ln8) * 1024 + scs8;   \
    const u16* pa2 = A_ + (size_t)(bm + wid * 32 + 16 + ln8) * 1024 + scs8;   \
    const u16* pa3 = A_ + (size_t)(bm + wid * 32 + 24 + ln8) * 1024 + scs8;   \
    const u16* pb0 = Bt_ + (size_t)(bn + wid * 16 +  0 + ln8) * 1024 + scs8;  \
    const u16* pb1 = Bt_ + (size_t)(bn + wid * 16 +  8 + ln8) * 1024 + scs8;  \
    bf16x8 a0[4], b0[4], a1[4], b1[4];                                        \
    STAGE6(0, 49152)                                                          \
    STAGE6(16384, 57344)                                                      \
    asm volatile("s_waitcnt vmcnt(6)" ::: "memory");                          \
    __builtin_amdgcn_s_barrier();                                             \
    _Pragma("unroll")                                                         \
    for (int n = 0; n < 16; ++n) {                                            \
        const int rdA = (n % 3) * 16384;                                      \
        const int rdB = 49152 + (n % 3) * 8192;                               \
        const int stA = ((n + 2) % 3) * 16384;                                \
        const int stB = 49152 + ((n + 2) % 3) * 8192;                         \
        const u16* Ab = &sAB[rdA + (wr * 64 + l15) * 64];                     \
        const u16* Bb = &sAB[rdB + (wc * 64 + l15) * 64];                     \
        _Pragma("unroll")                                                     \
        for (int mi = 0; mi < 4; mi++)                                        \
            a0[mi] = *(const bf16x8*)&Ab[mi * 1024 + sw0];                    \
        _Pragma("unroll")                                                     \
        for (int nj = 0; nj < 4; nj++)                                        \
            b0[nj] = *(const bf16x8*)&Bb[nj * 1024 + sw0];                    \
        __builtin_amdgcn_sched_barrier(0);                                    \
        if (n > 0) {                                                          \
            asm volatile("s_waitcnt lgkmcnt(8)" ::: "memory");                \
            __builtin_amdgcn_sched_barrier(0);                                \
            MFMA16(a1, b1)                                                    \
            __builtin_amdgcn_sched_barrier(0);                                \
        }                                                                     \
        asm volatile("" ::: "memory");                                        \
        __builtin_amdgcn_s_barrier();                                         \
        if (n + 2 < 16) STAGE6(stA, stB)                                      \
        _Pragma("unroll")                                                     \
        for (int mi = 0; mi < 4; mi++)                                        \
            a1[mi] = *(const bf16x8*)&Ab[mi * 1024 + sw1];                    \
        _Pragma("unroll")                                                     \
        for (int nj = 0; nj < 4; nj++)                                        \
            b1[nj] = *(const bf16x8*)&Bb[nj * 1024 + sw1];                    \
        __builtin_amdgcn_sched_barrier(0);                                    \
        asm volatile("s_waitcnt lgkmcnt(8)" ::: "memory");                    \
        __builtin_amdgcn_sched_barrier(0);                                    \
        MFMA16(a0, b0)                                                        \
        __builtin_amdgcn_sched_barrier(0);                                    \
        if (n < 14) {                                                         \
            asm volatile("s_waitcnt vmcnt(6)" ::: "memory");                  \
            asm volatile("" ::: "memory");                                    \
            __builtin_amdgcn_s_barrier();                                     \
        } else if (n == 14) {                                                 \
            asm volatile("s_waitcnt vmcnt(0)" ::: "memory");                  \
            asm volatile("" ::: "memory");                                    \
            __builtin_amdgcn_s_barrier();                                     \
        }                                                                     \
    }                                                                         \
    asm volatile("s_waitcnt lgkmcnt(0)" ::: "memory");                        \
    __builtin_amdgcn_sched_barrier(0);                                        \
    MFMA16(a1, b1)

// R4-style GEMM core (gemm_out): BM=BN=128, 4 waves, 64 KiB dbuf,
// counted vmcnt(8).  Measured-good inside R4's best-total run (2 blocks/CU,
// grid 512 = 2.0 rounds).
#define OSTAGE8(A_, Bt_, n_)                                                  \
    {                                                                         \
        const int dst = ((n_) & 1) * 8192;                                    \
        _Pragma("unroll")                                                     \
        for (int i = 0; i < 4; i++) {                                         \
            async_load16(&A_[(size_t)(bm + wid * 32 + i * 8 + ln8) * 1024 +   \
                             (n_) * 64 + scs8],                               \
                         &sAB[dst + wid * 2048 + i * 512 + lane * 8]);        \
            async_load16(&Bt_[(size_t)(bn + wid * 32 + i * 8 + ln8) * 1024 +  \
                              (n_) * 64 + scs8],                              \
                         &sAB[16384 + dst + wid * 2048 + i * 512 + lane * 8]);\
        }                                                                     \
    }

#define OKLOOP(A_, Bt_)                                                       \
    OSTAGE8(A_, Bt_, 0)                                                       \
    for (int n = 0; n < 16; ++n) {                                            \
        if (n + 1 < 16) {                                                     \
            OSTAGE8(A_, Bt_, n + 1)                                           \
            asm volatile("s_waitcnt vmcnt(8)" ::: "memory");                  \
        } else {                                                              \
            asm volatile("s_waitcnt vmcnt(0)" ::: "memory");                  \
        }                                                                     \
        __builtin_amdgcn_s_barrier();                                         \
        asm volatile("" ::: "memory");                                        \
        const int buf = (n & 1) * 8192;                                       \
        const u16* Ab = &sAB[buf + (wr * 64 + l15) * 64];                     \
        const u16* Bb = &sAB[16384 + buf + (wc * 64 + l15) * 64];             \
        bf16x8 a0[4], b0[4], a1[4], b1[4];                                    \
        _Pragma("unroll")                                                     \
        for (int mi = 0; mi < 4; mi++)                                        \
            a0[mi] = *(const bf16x8*)&Ab[mi * 1024 + sw0];                    \
        _Pragma("unroll")                                                     \
        for (int nj = 0; nj < 4; nj++)                                        \
            b0[nj] = *(const bf16x8*)&Bb[nj * 1024 + sw0];                    \
        __builtin_amdgcn_sched_barrier(0);                                    \
        _Pragma("unroll")                                                     \
        for (int mi = 0; mi < 4; mi++)                                        \
            a1[mi] = *(const bf16x8*)&Ab[mi * 1024 + sw1];                    \
        _Pragma("unroll")                                                     \
        for (int nj = 0; nj < 4; nj++)                                        \
            b1[nj] = *(const bf16x8*)&Bb[nj * 1024 + sw1];                    \
        asm volatile("s_waitcnt lgkmcnt(8)" ::: "memory");                    \
        __builtin_amdgcn_sched_barrier(0);                                    \
        MFMA16(a0, b0)                                                        \
        asm volatile("s_waitcnt lgkmcnt(0)" ::: "memory");                    \
        __builtin_amdgcn_sched_barrier(0);                                    \
        MFMA16(a1, b1)                                                        \
        __builtin_amdgcn_sched_barrier(0);                                    \
        asm volatile("" ::: "memory");                                        \
        __builtin_amdgcn_s_barrier();                                         \
    }

// bijective XCD swizzle (nwg % 8 == 0 for both GEMM grids)
#define XCD_SWIZZLE(BM_, BN_)                                                 \
    const int nwg = gridDim.x * gridDim.y;                                    \
    int orig = blockIdx.y * gridDim.x + blockIdx.x;                           \
    int wg = (orig & 7) * (nwg >> 3) + (orig >> 3);                           \
    const int bm = (wg / gridDim.x) * (BM_), bn = (wg % gridDim.x) * (BN_);

// ---------------------------------------------------------------------------
// QKV GEMM with fused rope+elu+mask epilogue -> bf16 head-major qb/kb/vb.
// grid (24, 32) = 768 blocks = 3.0 perfect rounds at 1 block/CU.
__global__ __launch_bounds__(512, 2) void gemm_qkv_kernel(
    const u16* __restrict__ A, const u16* __restrict__ Bt,
    const float* __restrict__ bias, const float* __restrict__ mask,
    const float* __restrict__ cosT, const float* __restrict__ sinT,
    u16* __restrict__ qb, u16* __restrict__ kb, u16* __restrict__ vb) {
    __shared__ u16 sAB[73728];                 // 144 KiB, triple-buffered
    const int tid  = threadIdx.x;
    const int wid  = tid >> 6, lane = tid & 63;
    const int wr = wid >> 1, wc = wid & 1;
    const int l15 = lane & 15, quad = lane >> 4;
    const int ln8 = lane >> 3;
    const int scs8 = ((lane & 7) ^ ln8) * 8;
    const int sw0 = (quad ^ (l15 & 7)) * 8;
    const int sw1 = ((4 + quad) ^ (l15 & 7)) * 8;
    XCD_SWIZZLE(256, 128)

    f32x4 acc[4][4];
#pragma unroll
    for (int i = 0; i < 4; i++)
#pragma unroll
        for (int j = 0; j < 4; j++) acc[i][j] = {0.f, 0.f, 0.f, 0.f};

    KLOOP(A, Bt)

    // ---- fused epilogue
    const int colbase = bn + wc * 64;          // multiple of 64
    const int region  = colbase >> 10;         // 0=q 1=k 2=v
    const int nh      = (colbase & 1023) >> 6;
    float bc[4];
#pragma unroll
    for (int nj = 0; nj < 4; nj++) bc[nj] = bias[colbase + nj * 16 + l15];
    u16* outp = (region == 0) ? qb : (region == 1) ? kb : vb;

#pragma unroll
    for (int mi = 0; mi < 4; mi++) {
#pragma unroll
        for (int r = 0; r < 4; r++) {
            int row = bm + wr * 64 + mi * 16 + quad * 4 + r;
            int b = row >> 11, s = row & (S_ - 1);
            size_t obase = ((size_t)(b * 16 + nh) * S_ + s) * 64;
            if (region < 2) {
                float mfac = (region == 0) ? 0.125f : mask[row];
#pragma unroll
                for (int p = 0; p < 2; p++) {
                    int d1 = p * 16 + l15;
                    float c  = cosT[s * 32 + d1];
                    float sn = sinT[s * 32 + d1];
                    float x1 = acc[mi][p][r]     + bc[p];
                    float x2 = acc[mi][p + 2][r] + bc[p + 2];
                    float r1 = x1 * c - x2 * sn;
                    float r2 = x2 * c + x1 * sn;
                    outp[obase + d1]      = f2bf(elu_k(r1) * mfac);
                    outp[obase + d1 + 32] = f2bf(elu_k(r2) * mfac);
                }
            } else {
                float mfac = mask[row];
#pragma unroll
                for (int nj = 0; nj < 4; nj++)
                    outp[obase + nj * 16 + l15] =
                        f2bf((acc[mi][nj][r] + bc[nj]) * mfac);
            }
        }
    }
}

// ---------------------------------------------------------------------------
// Output projection GEMM: C fp32 = A @ Bt^T + bias.
// R4 config: 128x128, 4 waves, 64 KiB, grid (8, 64) = 512 = 2.0 rounds at
// 2 blocks/CU — measured-good for the "rest" in R4's best-total run.
__global__ __launch_bounds__(256, 2) void gemm_out_kernel(
    const u16* __restrict__ A, const u16* __restrict__ Bt,
    const float* __restrict__ bias, float* __restrict__ C, int N) {
    __shared__ u16 sAB[32768];                 // 64 KiB
    const int tid  = threadIdx.x;
    const int wid  = tid >> 6, lane = tid & 63;
    const int wr = wid >> 1, wc = wid & 1;
    const int l15 = lane & 15, quad = lane >> 4;
    const int ln8 = lane >> 3;
    const int scs8 = ((lane & 7) ^ ln8) * 8;
    const int sw0 = (quad ^ (l15 & 7)) * 8;
    const int sw1 = ((4 + quad) ^ (l15 & 7)) * 8;
    XCD_SWIZZLE(128, 128)

    f32x4 acc[4][4];
#pragma unroll
    for (int i = 0; i < 4; i++)
#pragma unroll
        for (int j = 0; j < 4; j++) acc[i][j] = {0.f, 0.f, 0.f, 0.f};

    OKLOOP(A, Bt)

#pragma unroll
    for (int mi = 0; mi < 4; mi++) {
#pragma unroll
        for (int nj = 0; nj < 4; nj++) {
            int col = bn + wc * 64 + nj * 16 + l15;
            float bcol = bias[col];
#pragma unroll
            for (int r = 0; r < 4; r++) {
                int row = bm + wr * 64 + mi * 16 + quad * 4 + r;
                C[(size_t)row * N + col] = acc[mi][nj][r] + bcol;
            }
        }
    }
}

// ---------------------------------------------------------------------------
// kv partials from bf16 head-major k,v: grid (64 bn, NCH).
__global__ __launch_bounds__(256) void kv_part_kernel(
    const u16* __restrict__ kb, const u16* __restrict__ vb,
    float* __restrict__ kvpart, float* __restrict__ kspart) {
    int bn = blockIdx.x;
    const int rows = S_ / NCH;              // 128
    int s0 = blockIdx.y * rows;
    int tid = threadIdx.x;
    int ti = tid >> 4, tj = tid & 15;
    __shared__ float ks[16][64], vs[16][64];
    float acc[4][4] = {};
    float ksacc = 0.f;
    const u16* kbase = kb + (size_t)bn * (S_ * 64) + (size_t)s0 * 64;
    const u16* vbase = vb + (size_t)bn * (S_ * 64) + (size_t)s0 * 64;
    for (int ss = 0; ss < rows; ss += 16) {
        {
            int half = tid >> 7;
            int c = tid & 127;
            int rr = c >> 3, col = (c & 7) * 8;
            const u16* src = (half ? vbase : kbase) + (size_t)(ss + rr) * 64 + col;
            uint4 raw = *(const uint4*)src;
            float* dst = half ? &vs[rr][col] : &ks[rr][col];
            dst[0] = bfl(raw.x); dst[1] = bfh(raw.x);
            dst[2] = bfl(raw.y); dst[3] = bfh(raw.y);
            dst[4] = bfl(raw.z); dst[5] = bfh(raw.z);
            dst[6] = bfl(raw.w); dst[7] = bfh(raw.w);
        }
        __syncthreads();
#pragma unroll
        for (int r = 0; r < 16; r++) {
            float a[4], bb[4];
#pragma unroll
            for (int i = 0; i < 4; i++) a[i] = ks[r][ti * 4 + i];
#pragma unroll
            for (int j = 0; j < 4; j++) bb[j] = vs[r][tj * 4 + j];
#pragma unroll
            for (int i = 0; i < 4; i++)
#pragma unroll
                for (int j = 0; j < 4; j++)
                    acc[i][j] = fmaf(a[i], bb[j], acc[i][j]);
        }
        if (tid < 64) {
#pragma unroll
            for (int r = 0; r < 16; r++) ksacc += ks[r][tid];
        }
        __syncthreads();
    }
    size_t obase = ((size_t)blockIdx.y * 64 + bn) * 4096;
#pragma unroll
    for (int i = 0; i < 4; i++)
#pragma unroll
        for (int j = 0; j < 4; j++)
            kvpart[obase + (size_t)(ti * 4 + i) * 64 + tj * 4 + j] = acc[i][j];
    if (tid < 64)
        kspart[((size_t)blockIdx.y * 64 + bn) * 64 + tid] = ksacc;
}

// sum NCH partials for kv (262144) and ksum (4096) in one launch
__global__ __launch_bounds__(256) void reduce_part_kernel(
    const float* __restrict__ kvpart, const float* __restrict__ kspart,
    float* __restrict__ kvb, float* __restrict__ ksum) {
    int i = blockIdx.x * 256 + threadIdx.x;
    if (i < 262144) {
        float s = 0.f;
#pragma unroll
        for (int c = 0; c < NCH; c++) s += kvpart[(size_t)c * 262144 + i];
        kvb[i] = s;
    } else if (i < 262144 + 4096) {
        int j = i - 262144;
        float s = 0.f;
#pragma unroll
        for (int c = 0; c < NCH; c++) s += kspart[(size_t)c * 4096 + j];
        ksum[j] = s;
    }
}

// ---------------------------------------------------------------------------
// MFMA combine: per (b,n), num = Q[256x64] @ kv[64x64], den via ksum column.
__global__ __launch_bounds__(256) void combine_kernel(
    const u16* __restrict__ qb, const float* __restrict__ kvb,
    const float* __restrict__ ksum, const float* __restrict__ g,
    const float* __restrict__ coeffp, u16* __restrict__ cmb) {
    int bn = blockIdx.x;
    int b = bn >> 4, n = bn & 15;
    __shared__ u16 qs[256 * 72];
    __shared__ u16 kvT[64 * 72];
    __shared__ u16 ksl[128];
    int tid = threadIdx.x;
    int s0 = blockIdx.y * 256;

    const u16* qsrc = qb + (size_t)bn * (S_ * 64) + (size_t)s0 * 64;
    for (int c = tid; c < 2048; c += 256) {
        int t = c >> 3, k8 = (c & 7) * 8;
        float4 tmp = *(const float4*)(qsrc + (size_t)c * 8);
        *(float4*)&qs[t * 72 + k8] = tmp;
    }
    for (int c = tid; c < 1024; c += 256) {
        int i = c >> 4, d4 = (c & 15) * 4;
        float4 kvv = *(const float4*)&kvb[(size_t)bn * 4096 + i * 64 + d4];
        kvT[(d4 + 0) * 72 + i] = f2bf(kvv.x);
        kvT[(d4 + 1) * 72 + i] = f2bf(kvv.y);
        kvT[(d4 + 2) * 72 + i] = f2bf(kvv.z);
        kvT[(d4 + 3) * 72 + i] = f2bf(kvv.w);
    }
    if (tid < 64)        ksl[tid] = f2bf(ksum[bn * 64 + tid]);
    else if (tid < 128)  ksl[tid] = 0;
    __syncthreads();

    int wave = tid >> 6, lane = tid & 63;
    int l15 = lane & 15, quad = lane >> 4;
    int wt = wave * 64;

    int ko0 = (l15 == 0) ? quad * 8      : 64;
    int ko1 = (l15 == 0) ? 32 + quad * 8 : 64;
    bf16x8 ksf0 = *(const bf16x8*)&ksl[ko0];
    bf16x8 ksf1 = *(const bf16x8*)&ksl[ko1];

    bf16x8 bfr0[4], bfr1[4];
#pragma unroll
    for (int nj = 0; nj < 4; nj++) {
        bfr0[nj] = *(const bf16x8*)&kvT[(nj * 16 + l15) * 72 + quad * 8];
        bfr1[nj] = *(const bf16x8*)&kvT[(nj * 16 + l15) * 72 + 32 + quad * 8];
    }

    f32x4 acc[4][4], dacc[4];
#pragma unroll
    for (int i = 0; i < 4; i++) {
        dacc[i] = {0.f, 0.f, 0.f, 0.f};
#pragma unroll
        for (int j = 0; j < 4; j++) acc[i][j] = {0.f, 0.f, 0.f, 0.f};
    }

#pragma unroll
    for (int mi = 0; mi < 4; mi++) {
        bf16x8 a0 = *(const bf16x8*)&qs[(wt + mi * 16 + l15) * 72 + quad * 8];
        bf16x8 a1 = *(const bf16x8*)&qs[(wt + mi * 16 + l15) * 72 + 32 + quad * 8];
        dacc[mi] = __builtin_amdgcn_mfma_f32_16x16x32_bf16(a0, ksf0, dacc[mi], 0, 0, 0);
        dacc[mi] = __builtin_amdgcn_mfma_f32_16x16x32_bf16(a1, ksf1, dacc[mi], 0, 0, 0);
#pragma unroll
        for (int nj = 0; nj < 4; nj++) {
            acc[mi][nj] = __builtin_amdgcn_mfma_f32_16x16x32_bf16(
                a0, bfr0[nj], acc[mi][nj], 0, 0, 0);
            acc[mi][nj] = __builtin_amdgcn_mfma_f32_16x16x32_bf16(
                a1, bfr1[nj], acc[mi][nj], 0, 0, 0);
        }
    }

    float coeff = *coeffp;
#pragma unroll
    for (int mi = 0; mi < 4; mi++) {
#pragma unroll
        for (int r = 0; r < 4; r++) {
            int s = s0 + wt + mi * 16 + quad * 4 + r;
            int t = b * S_ + s;
            float den = __shfl(dacc[mi][r], lane & 48) + 1e-6f;
            float gv = g[t];
            float w1 = gv / den + (1.f - gv) * coeff;
#pragma unroll
            for (int nj = 0; nj < 4; nj++) {
                int d = nj * 16 + l15;
                cmb[(size_t)t * H_ + n * 64 + d] = f2bf(acc[mi][nj][r] * w1);
            }
        }
    }
}

// ---------------------------------------------------------------------------
extern "C" void kernel_launch(void* const* d_in, const int* in_sizes, int n_in,
                              void* d_out, int out_size, void* d_ws, size_t ws_size,
                              hipStream_t stream) {
    const float* hs    = (const float*)d_in[0];
    const float* mask  = (const float*)d_in[1];
    const float* Wq    = (const float*)d_in[2];
    const float* bq    = (const float*)d_in[3];
    const float* Wk    = (const float*)d_in[4];
    const float* bk    = (const float*)d_in[5];
    const float* Wv    = (const float*)d_in[6];
    const float* bv    = (const float*)d_in[7];
    const float* Wo    = (const float*)d_in[8];
    const float* bo    = (const float*)d_in[9];
    const float* Wg    = (const float*)d_in[10];
    const float* bg    = (const float*)d_in[11];
    const float* decay = (const float*)d_in[12];
    const float* gate  = (const float*)d_in[13];
    float* out = (float*)d_out;

    // ---- workspace layout
    float* ws     = (float*)d_ws;
    float* kvb    = ws;                         // 262144
    float* ksum   = kvb + 262144;               // 4096
    float* gbuf   = ksum + 4096;                // 8192
    float* coeff  = gbuf + 8192;                // 64
    float* cosT   = coeff + 64;                 // 65536
    float* sinT   = cosT + 65536;               // 65536
    float* bqkv   = sinT + 65536;               // 3072 (+pad to 4096)
    float* kspart = bqkv + 4096;                // NCH*4096 = 65536
    float* kvpart = kspart + 65536;             // NCH*262144 = 4194304
    u16*   hsb    = (u16*)(kvpart + 4194304);   // T*1024
    u16*   Wt     = hsb + (size_t)T_ * H_;      // 4096*1024
    u16*   WoT    = Wt + (size_t)3072 * H_;
    u16*   qb     = Wt + (size_t)4096 * H_;     // T*1024 head-major
    u16*   kb     = qb + (size_t)T_ * H_;
    u16*   vb     = kb + (size_t)T_ * H_;
    u16*   cmb    = vb + (size_t)T_ * H_;

    pre_kernel<<<T_ + 1024 + 270, 256, 0, stream>>>(
        hs, Wg, bg, Wq, Wk, Wv, Wo, decay, gate, bq, bk, bv,
        hsb, gbuf, Wt, coeff, cosT, sinT, bqkv);

    gemm_qkv_kernel<<<dim3(3072 / 128, T_ / 256), 512, 0, stream>>>(
        hsb, Wt, bqkv, mask, cosT, sinT, qb, kb, vb);

    kv_part_kernel<<<dim3(B_ * NH, NCH), 256, 0, stream>>>(
        kb, vb, kvpart, kspart);
    reduce_part_kernel<<<(262144 + 4096 + 255) / 256, 256, 0, stream>>>(
        kvpart, kspart, kvb, ksum);

    combine_kernel<<<dim3(B_ * NH, S_ / 256), 256, 0, stream>>>(
        qb, kvb, ksum, gbuf, coeff, cmb);

    gemm_out_kernel<<<dim3(H_ / 128, T_ / 128), 256, 0, stream>>>(
        cmb, WoT, bo, out, H_);
}

// Round 9
// 234.874 us; speedup vs baseline: 1.0633x; 1.0230x over previous
//
#include <hip/hip_runtime.h>
#include <math.h>

#define B_   4
#define S_   2048
#define H_   1024
#define NH   16
#define HD   64
#define T_   (B_ * S_)       // 8192 tokens
#define NCH  16              // kv S-chunks

typedef unsigned short u16;
typedef __bf16 bf16x8 __attribute__((ext_vector_type(8)));
typedef float  f32x4  __attribute__((ext_vector_type(4)));

// ---------------------------------------------------------------------------
__device__ __forceinline__ float elu_k(float x) {
    return (x > 0.f ? x : (expf(x) - 1.f)) + 1.000001f;
}

__device__ __forceinline__ u16 f2bf(float x) {
    union { float f; unsigned int u; } v; v.f = x;
    unsigned int r = v.u + 0x7FFFu + ((v.u >> 16) & 1u);
    return (u16)(r >> 16);
}

__device__ __forceinline__ float bfl(unsigned int u) {
    union { unsigned int u; float f; } v; v.u = u << 16; return v.f;
}
__device__ __forceinline__ float bfh(unsigned int u) {
    union { unsigned int u; float f; } v; v.u = u & 0xFFFF0000u; return v.f;
}

// async global->LDS, 16 B/lane; LDS side uses lane0's base + lane*16,
// global side is per-lane.
__device__ __forceinline__ void async_load16(const u16* g, u16* l) {
    __builtin_amdgcn_global_load_lds(
        (const __attribute__((address_space(1))) void*)g,
        (__attribute__((address_space(3))) void*)l,
        16, 0, 0);
}

// ---------------------------------------------------------------------------
// Merged prologue: cvt_gate (blocks 0..8191) | pack_w (8192..9215) |
// prep (9216..9485).  Sections fully independent (disjoint reads/writes).
__global__ __launch_bounds__(256) void pre_kernel(
    const float* __restrict__ hs, const float* __restrict__ Wg,
    const float* __restrict__ bg, const float* __restrict__ Wq,
    const float* __restrict__ Wk, const float* __restrict__ Wv,
    const float* __restrict__ Wo, const float* __restrict__ decay,
    const float* __restrict__ gate, const float* __restrict__ bq,
    const float* __restrict__ bk, const float* __restrict__ bv,
    u16* __restrict__ hsb, float* __restrict__ gbuf, u16* __restrict__ Wt,
    float* __restrict__ coeff, float* __restrict__ cosT,
    float* __restrict__ sinT, float* __restrict__ bqkv) {
    __shared__ u16 tile[64][65];
    __shared__ float wsum[4];
    const int blk = blockIdx.x;
    const int tid = threadIdx.x;

    if (blk < T_) {
        // ---- cvt_gate: hs->bf16 + gate gemv, one block per token
        int t = blk;
        float4 f = ((const float4*)(hs + (size_t)t * H_))[tid];
        float4 w = ((const float4*)Wg)[tid];
        ushort4 u;
        u.x = f2bf(f.x); u.y = f2bf(f.y); u.z = f2bf(f.z); u.w = f2bf(f.w);
        ((ushort4*)(hsb + (size_t)t * H_))[tid] = u;
        float s = f.x * w.x + f.y * w.y + f.z * w.z + f.w * w.w;
#pragma unroll
        for (int off = 32; off > 0; off >>= 1) s += __shfl_down(s, off);
        if ((tid & 63) == 0) wsum[tid >> 6] = s;
        __syncthreads();
        if (tid == 0) {
            float tot = wsum[0] + wsum[1] + wsum[2] + wsum[3];
            gbuf[t] = 1.f / (1.f + expf(-(tot + bg[0])));
        }
    } else if (blk < T_ + 1024) {
        // ---- pack_w: Wt[w*1024 + n][k] = bf16(W_w[k][n])
        int idx = blk - T_;
        int wsel = idx >> 8, rem = idx & 255;
        int nt = (rem & 15) * 64, kt = (rem >> 4) * 64;
        const float* W = (wsel == 0) ? Wq : (wsel == 1) ? Wk :
                         (wsel == 2) ? Wv : Wo;
#pragma unroll
        for (int it = 0; it < 16; it++) {
            int i = it * 256 + tid;
            int kr = i >> 6, nc = i & 63;
            tile[kr][nc] = f2bf(W[(size_t)(kt + kr) * H_ + nt + nc]);
        }
        __syncthreads();
        size_t wbase = (size_t)wsel * H_;
#pragma unroll
        for (int it = 0; it < 16; it++) {
            int i = it * 256 + tid;
            int nr = i >> 6, kc = i & 63;
            Wt[(wbase + nt + nr) * H_ + kt + kc] = tile[kc][nr];
        }
    } else {
        // ---- prep: rope tables + packed bias + coeff
        int idx = (blk - (T_ + 1024)) * 256 + tid;
        if (idx < S_ * 32) {
            int s = idx >> 5, i = idx & 31;
            float inv = powf(10000.f, -(2.f * (float)i) / 64.f);
            float f = (float)s * inv;
            cosT[idx] = cosf(f);
            sinT[idx] = sinf(f);
        } else if (idx < S_ * 32 + 3072) {
            int i = idx - S_ * 32;
            bqkv[i] = (i < 1024) ? bq[i] : (i < 2048) ? bk[i - 1024]
                                                      : bv[i - 2048];
        } else if (idx == S_ * 32 + 3072) {
            float g0 = gate[0], g1 = gate[1], g2 = gate[2];
            float mx = fmaxf(g0, fmaxf(g1, g2));
            float e0 = expf(g0 - mx), e1 = expf(g1 - mx), e2 = expf(g2 - mx);
            float inv = 1.f / (e0 + e1 + e2);
            float es[3] = {e0, e1, e2};
            float c = 0.f;
            for (int m = 0; m < 3; m++) {
                float ds = 1.f / (1.f + expf(-decay[m]));
                c += es[m] * inv * (1.f - ds);
            }
            *coeff = c;
        }
    }
}

// ---------------------------------------------------------------------------
// GEMM core v7 (qkv): v6 geometry/pipeline, but ONE barrier per K-tile.
// BM=256, BN=128, BK=64, 8 waves, triple-buffered LDS (144 KiB).
// Per tile n:
//   issue G0(n) 8 ds_read | issue G1(n) 8 ds_read | stage(n+2) 6 vm-loads
//   lgkm(8) -> M0(n)   [G1 drains under M0's 620cy matrix-pipe occupancy]
//   lgkm(0) -> M1(n)   [usually satisfied]
//   vmcnt(6) [drains stage(n+1); stage(n+2) stays in flight] ; barrier
// Race ledger (single barrier, drift bounded to one tile by barrier(n)):
//  - stage(n+2) writes buf (n+2)%3 == buf (n-1)%3; its last readers are
//    tile n-1's G reads, drained per-wave at lgkm(0) before M1(n-1), which
//    precedes barrier(n-1) < stage(n+2) issue (tile n). Cross-wave: no wave
//    enters tile n before all exit tile n-1 (barrier).
//  - G0/G1(n) read buf n%3, written by stage(n) (issued tile n-2), drained
//    by vmcnt(6) at end of tile n-1 (outstanding there = stage(n) 6 +
//    stage(n+1) 6 -> drains stage(n)) + barrier.
//  - prologue: stage(0), stage(1); vmcnt(6) drains stage(0); barrier.
//  - n=14: no stage(16) -> vmcnt(0) drains stage(15). n=15: no stage/vmcnt.
//  - MFMA order M0(n),M1(n) identical to v6 -> bit-identical numerics.
//  - barrier count uniform across waves (all conditionals on uniform n).

#define STAGE6(AST, BST)                                                      \
    {                                                                         \
        async_load16(pa0, &sAB[(AST) + wid * 2048 + lane * 8]);               \
        async_load16(pa1, &sAB[(AST) + wid * 2048 + 512 + lane * 8]);         \
        async_load16(pa2, &sAB[(AST) + wid * 2048 + 1024 + lane * 8]);        \
        async_load16(pa3, &sAB[(AST) + wid * 2048 + 1536 + lane * 8]);        \
        async_load16(pb0, &sAB[(BST) + wid * 1024 + lane * 8]);               \
        async_load16(pb1, &sAB[(BST) + wid * 1024 + 512 + lane * 8]);         \
        pa0 += 64; pa1 += 64; pa2 += 64; pa3 += 64; pb0 += 64; pb1 += 64;     \
    }

#define MFMA16(AV, BV)                                                        \
    __builtin_amdgcn_s_setprio(1);                                            \
    _Pragma("unroll")                                                         \
    for (int mi = 0; mi < 4; mi++)                                            \
        _Pragma("unroll")                                                     \
        for (int nj = 0; nj < 4; nj++)                                        \
            acc[mi][nj] = __builtin_amdgcn_mfma_f32_16x16x32_bf16(            \
                AV[mi], BV[nj], acc[mi][nj], 0, 0, 0);                        \
    __builtin_amdgcn_s_setprio(0);

#define KLOOP(A_, Bt_)                                                        \
    const u16* pa0 = A_ + (size_t)(bm + wid * 32 +  0 + ln8) * 1024 + scs8;   \
    const u16* pa1 = A_ + (size_t)(bm + wid * 32 +  8 + ln8) * 1024 + scs8;   \
    const u16* pa2 = A_ + (size_t)(bm + wid * 32 + 16 + ln8) * 1024 + scs8;   \
    const u16* pa3 = A_ + (size_t)(bm + wid * 32 + 24 + ln8) * 1024 + scs8;   \
    const u16* pb0 = Bt_ + (size_t)(bn + wid * 16 +  0 + ln8) * 1024 + scs8;  \
    const u16* pb1 = Bt_ + (size_t)(bn + wid * 16 +  8 + ln8) * 1024 + scs8;  \
    bf16x8 a0[4], b0[4], a1[4], b1[4];                                        \
    STAGE6(0, 49152)                        /* stage tile 0 -> buf0 */        \
    STAGE6(16384, 57344)                    /* stage tile 1 -> buf1 */        \
    asm volatile("s_waitcnt vmcnt(6)" ::: "memory");  /* tile0 landed */      \
    __builtin_amdgcn_s_barrier();                                             \
    _Pragma("unroll")                                                         \
    for (int n = 0; n < 16; ++n) {                                            \
        const int rdA = (n % 3) * 16384;                                      \
        const int rdB = 49152 + (n % 3) * 8192;                               \
        const int stA = ((n + 2) % 3) * 16384;                                \
        const int stB = 49152 + ((n + 2) % 3) * 8192;                         \
        const u16* Ab = &sAB[rdA + (wr * 64 + l15) * 64];                     \
        const u16* Bb = &sAB[rdB + (wc * 64 + l15) * 64];                     \
        /* issue all 16 ds_reads: kk0 batch first, then kk1 batch */          \
        _Pragma("unroll")                                                     \
        for (int mi = 0; mi < 4; mi++)                                        \
            a0[mi] = *(const bf16x8*)&Ab[mi * 1024 + sw0];                    \
        _Pragma("unroll")                                                     \
        for (int nj = 0; nj < 4; nj++)                                        \
            b0[nj] = *(const bf16x8*)&Bb[nj * 1024 + sw0];                    \
        __builtin_amdgcn_sched_barrier(0);                                    \
        _Pragma("unroll")                                                     \
        for (int mi = 0; mi < 4; mi++)                                        \
            a1[mi] = *(const bf16x8*)&Ab[mi * 1024 + sw1];                    \
        _Pragma("unroll")                                                     \
        for (int nj = 0; nj < 4; nj++)                                        \
            b1[nj] = *(const bf16x8*)&Bb[nj * 1024 + sw1];                    \
        __builtin_amdgcn_sched_barrier(0);                                    \
        /* prefetch next-next tile while reads drain */                       \
        if (n + 2 < 16) STAGE6(stA, stB)                                      \
        /* M0 under G1's drain */                                             \
        asm volatile("s_waitcnt lgkmcnt(8)" ::: "memory");                    \
        __builtin_amdgcn_sched_barrier(0);                                    \
        MFMA16(a0, b0)                                                        \
        __builtin_amdgcn_sched_barrier(0);                                    \
        asm volatile("s_waitcnt lgkmcnt(0)" ::: "memory");                    \
        __builtin_amdgcn_sched_barrier(0);                                    \
        MFMA16(a1, b1)                                                        \
        __builtin_amdgcn_sched_barrier(0);                                    \
        /* single rendezvous per tile */                                      \
        if (n < 14) {                                                         \
            asm volatile("s_waitcnt vmcnt(6)" ::: "memory");                  \
        } else if (n == 14) {                                                 \
            asm volatile("s_waitcnt vmcnt(0)" ::: "memory");                  \
        }                                                                     \
        asm volatile("" ::: "memory");                                        \
        __builtin_amdgcn_s_barrier();                                         \
    }

// R4-style GEMM core (gemm_out): BM=BN=128, 4 waves, 64 KiB dbuf,
// counted vmcnt(8), 2 blocks/CU.  Measured-good; unchanged.
#define OSTAGE8(A_, Bt_, n_)                                                  \
    {                                                                         \
        const int dst = ((n_) & 1) * 8192;                                    \
        _Pragma("unroll")                                                     \
        for (int i = 0; i < 4; i++) {                                         \
            async_load16(&A_[(size_t)(bm + wid * 32 + i * 8 + ln8) * 1024 +   \
                             (n_) * 64 + scs8],                               \
                         &sAB[dst + wid * 2048 + i * 512 + lane * 8]);        \
            async_load16(&Bt_[(size_t)(bn + wid * 32 + i * 8 + ln8) * 1024 +  \
                              (n_) * 64 + scs8],                              \
                         &sAB[16384 + dst + wid * 2048 + i * 512 + lane * 8]);\
        }                                                                     \
    }

#define OKLOOP(A_, Bt_)                                                       \
    OSTAGE8(A_, Bt_, 0)                                                       \
    for (int n = 0; n < 16; ++n) {                                            \
        if (n + 1 < 16) {                                                     \
            OSTAGE8(A_, Bt_, n + 1)                                           \
            asm volatile("s_waitcnt vmcnt(8)" ::: "memory");                  \
        } else {                                                              \
            asm volatile("s_waitcnt vmcnt(0)" ::: "memory");                  \
        }                                                                     \
        __builtin_amdgcn_s_barrier();                                         \
        asm volatile("" ::: "memory");                                        \
        const int buf = (n & 1) * 8192;                                       \
        const u16* Ab = &sAB[buf + (wr * 64 + l15) * 64];                     \
        const u16* Bb = &sAB[16384 + buf + (wc * 64 + l15) * 64];             \
        bf16x8 a0[4], b0[4], a1[4], b1[4];                                    \
        _Pragma("unroll")                                                     \
        for (int mi = 0; mi < 4; mi++)                                        \
            a0[mi] = *(const bf16x8*)&Ab[mi * 1024 + sw0];                    \
        _Pragma("unroll")                                                     \
        for (int nj = 0; nj < 4; nj++)                                        \
            b0[nj] = *(const bf16x8*)&Bb[nj * 1024 + sw0];                    \
        __builtin_amdgcn_sched_barrier(0);                                    \
        _Pragma("unroll")                                                     \
        for (int mi = 0; mi < 4; mi++)                                        \
            a1[mi] = *(const bf16x8*)&Ab[mi * 1024 + sw1];                    \
        _Pragma("unroll")                                                     \
        for (int nj = 0; nj < 4; nj++)                                        \
            b1[nj] = *(const bf16x8*)&Bb[nj * 1024 + sw1];                    \
        asm volatile("s_waitcnt lgkmcnt(8)" ::: "memory");                    \
        __builtin_amdgcn_sched_barrier(0);                                    \
        MFMA16(a0, b0)                                                        \
        asm volatile("s_waitcnt lgkmcnt(0)" ::: "memory");                    \
        __builtin_amdgcn_sched_barrier(0);                                    \
        MFMA16(a1, b1)                                                        \
        __builtin_amdgcn_sched_barrier(0);                                    \
        asm volatile("" ::: "memory");                                        \
        __builtin_amdgcn_s_barrier();                                         \
    }

// bijective XCD swizzle (nwg % 8 == 0 for both GEMM grids)
#define XCD_SWIZZLE(BM_, BN_)                                                 \
    const int nwg = gridDim.x * gridDim.y;                                    \
    int orig = blockIdx.y * gridDim.x + blockIdx.x;                           \
    int wg = (orig & 7) * (nwg >> 3) + (orig >> 3);                           \
    const int bm = (wg / gridDim.x) * (BM_), bn = (wg % gridDim.x) * (BN_);

// ---------------------------------------------------------------------------
// QKV GEMM with fused rope+elu+mask epilogue -> bf16 head-major qb/kb/vb.
// grid (24, 32) = 768 blocks = 3.0 perfect rounds at 1 block/CU.
__global__ __launch_bounds__(512, 2) void gemm_qkv_kernel(
    const u16* __restrict__ A, const u16* __restrict__ Bt,
    const float* __restrict__ bias, const float* __restrict__ mask,
    const float* __restrict__ cosT, const float* __restrict__ sinT,
    u16* __restrict__ qb, u16* __restrict__ kb, u16* __restrict__ vb) {
    __shared__ u16 sAB[73728];                 // 144 KiB, triple-buffered
    const int tid  = threadIdx.x;
    const int wid  = tid >> 6, lane = tid & 63;
    const int wr = wid >> 1, wc = wid & 1;
    const int l15 = lane & 15, quad = lane >> 4;
    const int ln8 = lane >> 3;
    const int scs8 = ((lane & 7) ^ ln8) * 8;
    const int sw0 = (quad ^ (l15 & 7)) * 8;
    const int sw1 = ((4 + quad) ^ (l15 & 7)) * 8;
    XCD_SWIZZLE(256, 128)

    f32x4 acc[4][4];
#pragma unroll
    for (int i = 0; i < 4; i++)
#pragma unroll
        for (int j = 0; j < 4; j++) acc[i][j] = {0.f, 0.f, 0.f, 0.f};

    KLOOP(A, Bt)

    // ---- fused epilogue
    const int colbase = bn + wc * 64;          // multiple of 64
    const int region  = colbase >> 10;         // 0=q 1=k 2=v
    const int nh      = (colbase & 1023) >> 6;
    float bc[4];
#pragma unroll
    for (int nj = 0; nj < 4; nj++) bc[nj] = bias[colbase + nj * 16 + l15];
    u16* outp = (region == 0) ? qb : (region == 1) ? kb : vb;

#pragma unroll
    for (int mi = 0; mi < 4; mi++) {
#pragma unroll
        for (int r = 0; r < 4; r++) {
            int row = bm + wr * 64 + mi * 16 + quad * 4 + r;
            int b = row >> 11, s = row & (S_ - 1);
            size_t obase = ((size_t)(b * 16 + nh) * S_ + s) * 64;
            if (region < 2) {
                float mfac = (region == 0) ? 0.125f : mask[row];
#pragma unroll
                for (int p = 0; p < 2; p++) {
                    int d1 = p * 16 + l15;
                    float c  = cosT[s * 32 + d1];
                    float sn = sinT[s * 32 + d1];
                    float x1 = acc[mi][p][r]     + bc[p];
                    float x2 = acc[mi][p + 2][r] + bc[p + 2];
                    float r1 = x1 * c - x2 * sn;
                    float r2 = x2 * c + x1 * sn;
                    outp[obase + d1]      = f2bf(elu_k(r1) * mfac);
                    outp[obase + d1 + 32] = f2bf(elu_k(r2) * mfac);
                }
            } else {
                float mfac = mask[row];
#pragma unroll
                for (int nj = 0; nj < 4; nj++)
                    outp[obase + nj * 16 + l15] =
                        f2bf((acc[mi][nj][r] + bc[nj]) * mfac);
            }
        }
    }
}

// ---------------------------------------------------------------------------
// Output projection GEMM: C fp32 = A @ Bt^T + bias.
// R4 config: 128x128, 4 waves, 64 KiB, grid (8, 64) = 512 = 2.0 rounds at
// 2 blocks/CU.
__global__ __launch_bounds__(256, 2) void gemm_out_kernel(
    const u16* __restrict__ A, const u16* __restrict__ Bt,
    const float* __restrict__ bias, float* __restrict__ C, int N) {
    __shared__ u16 sAB[32768];                 // 64 KiB
    const int tid  = threadIdx.x;
    const int wid  = tid >> 6, lane = tid & 63;
    const int wr = wid >> 1, wc = wid & 1;
    const int l15 = lane & 15, quad = lane >> 4;
    const int ln8 = lane >> 3;
    const int scs8 = ((lane & 7) ^ ln8) * 8;
    const int sw0 = (quad ^ (l15 & 7)) * 8;
    const int sw1 = ((4 + quad) ^ (l15 & 7)) * 8;
    XCD_SWIZZLE(128, 128)

    f32x4 acc[4][4];
#pragma unroll
    for (int i = 0; i < 4; i++)
#pragma unroll
        for (int j = 0; j < 4; j++) acc[i][j] = {0.f, 0.f, 0.f, 0.f};

    OKLOOP(A, Bt)

#pragma unroll
    for (int mi = 0; mi < 4; mi++) {
#pragma unroll
        for (int nj = 0; nj < 4; nj++) {
            int col = bn + wc * 64 + nj * 16 + l15;
            float bcol = bias[col];
#pragma unroll
            for (int r = 0; r < 4; r++) {
                int row = bm + wr * 64 + mi * 16 + quad * 4 + r;
                C[(size_t)row * N + col] = acc[mi][nj][r] + bcol;
            }
        }
    }
}

// ---------------------------------------------------------------------------
// kv partials from bf16 head-major k,v: grid (64 bn, NCH).
__global__ __launch_bounds__(256) void kv_part_kernel(
    const u16* __restrict__ kb, const u16* __restrict__ vb,
    float* __restrict__ kvpart, float* __restrict__ kspart) {
    int bn = blockIdx.x;
    const int rows = S_ / NCH;              // 128
    int s0 = blockIdx.y * rows;
    int tid = threadIdx.x;
    int ti = tid >> 4, tj = tid & 15;
    __shared__ float ks[16][64], vs[16][64];
    float acc[4][4] = {};
    float ksacc = 0.f;
    const u16* kbase = kb + (size_t)bn * (S_ * 64) + (size_t)s0 * 64;
    const u16* vbase = vb + (size_t)bn * (S_ * 64) + (size_t)s0 * 64;
    for (int ss = 0; ss < rows; ss += 16) {
        {
            int half = tid >> 7;
            int c = tid & 127;
            int rr = c >> 3, col = (c & 7) * 8;
            const u16* src = (half ? vbase : kbase) + (size_t)(ss + rr) * 64 + col;
            uint4 raw = *(const uint4*)src;
            float* dst = half ? &vs[rr][col] : &ks[rr][col];
            dst[0] = bfl(raw.x); dst[1] = bfh(raw.x);
            dst[2] = bfl(raw.y); dst[3] = bfh(raw.y);
            dst[4] = bfl(raw.z); dst[5] = bfh(raw.z);
            dst[6] = bfl(raw.w); dst[7] = bfh(raw.w);
        }
        __syncthreads();
#pragma unroll
        for (int r = 0; r < 16; r++) {
            float a[4], bb[4];
#pragma unroll
            for (int i = 0; i < 4; i++) a[i] = ks[r][ti * 4 + i];
#pragma unroll
            for (int j = 0; j < 4; j++) bb[j] = vs[r][tj * 4 + j];
#pragma unroll
            for (int i = 0; i < 4; i++)
#pragma unroll
                for (int j = 0; j < 4; j++)
                    acc[i][j] = fmaf(a[i], bb[j], acc[i][j]);
        }
        if (tid < 64) {
#pragma unroll
            for (int r = 0; r < 16; r++) ksacc += ks[r][tid];
        }
        __syncthreads();
    }
    size_t obase = ((size_t)blockIdx.y * 64 + bn) * 4096;
#pragma unroll
    for (int i = 0; i < 4; i++)
#pragma unroll
        for (int j = 0; j < 4; j++)
            kvpart[obase + (size_t)(ti * 4 + i) * 64 + tj * 4 + j] = acc[i][j];
    if (tid < 64)
        kspart[((size_t)blockIdx.y * 64 + bn) * 64 + tid] = ksacc;
}

// sum NCH partials for kv (262144) and ksum (4096) in one launch
__global__ __launch_bounds__(256) void reduce_part_kernel(
    const float* __restrict__ kvpart, const float* __restrict__ kspart,
    float* __restrict__ kvb, float* __restrict__ ksum) {
    int i = blockIdx.x * 256 + threadIdx.x;
    if (i < 262144) {
        float s = 0.f;
#pragma unroll
        for (int c = 0; c < NCH; c++) s += kvpart[(size_t)c * 262144 + i];
        kvb[i] = s;
    } else if (i < 262144 + 4096) {
        int j = i - 262144;
        float s = 0.f;
#pragma unroll
        for (int c = 0; c < NCH; c++) s += kspart[(size_t)c * 4096 + j];
        ksum[j] = s;
    }
}

// ---------------------------------------------------------------------------
// MFMA combine: per (b,n), num = Q[256x64] @ kv[64x64], den via ksum column.
__global__ __launch_bounds__(256) void combine_kernel(
    const u16* __restrict__ qb, const float* __restrict__ kvb,
    const float* __restrict__ ksum, const float* __restrict__ g,
    const float* __restrict__ coeffp, u16* __restrict__ cmb) {
    int bn = blockIdx.x;
    int b = bn >> 4, n = bn & 15;
    __shared__ u16 qs[256 * 72];
    __shared__ u16 kvT[64 * 72];
    __shared__ u16 ksl[128];
    int tid = threadIdx.x;
    int s0 = blockIdx.y * 256;

    const u16* qsrc = qb + (size_t)bn * (S_ * 64) + (size_t)s0 * 64;
    for (int c = tid; c < 2048; c += 256) {
        int t = c >> 3, k8 = (c & 7) * 8;
        float4 tmp = *(const float4*)(qsrc + (size_t)c * 8);
        *(float4*)&qs[t * 72 + k8] = tmp;
    }
    for (int c = tid; c < 1024; c += 256) {
        int i = c >> 4, d4 = (c & 15) * 4;
        float4 kvv = *(const float4*)&kvb[(size_t)bn * 4096 + i * 64 + d4];
        kvT[(d4 + 0) * 72 + i] = f2bf(kvv.x);
        kvT[(d4 + 1) * 72 + i] = f2bf(kvv.y);
        kvT[(d4 + 2) * 72 + i] = f2bf(kvv.z);
        kvT[(d4 + 3) * 72 + i] = f2bf(kvv.w);
    }
    if (tid < 64)        ksl[tid] = f2bf(ksum[bn * 64 + tid]);
    else if (tid < 128)  ksl[tid] = 0;
    __syncthreads();

    int wave = tid >> 6, lane = tid & 63;
    int l15 = lane & 15, quad = lane >> 4;
    int wt = wave * 64;

    int ko0 = (l15 == 0) ? quad * 8      : 64;
    int ko1 = (l15 == 0) ? 32 + quad * 8 : 64;
    bf16x8 ksf0 = *(const bf16x8*)&ksl[ko0];
    bf16x8 ksf1 = *(const bf16x8*)&ksl[ko1];

    bf16x8 bfr0[4], bfr1[4];
#pragma unroll
    for (int nj = 0; nj < 4; nj++) {
        bfr0[nj] = *(const bf16x8*)&kvT[(nj * 16 + l15) * 72 + quad * 8];
        bfr1[nj] = *(const bf16x8*)&kvT[(nj * 16 + l15) * 72 + 32 + quad * 8];
    }

    f32x4 acc[4][4], dacc[4];
#pragma unroll
    for (int i = 0; i < 4; i++) {
        dacc[i] = {0.f, 0.f, 0.f, 0.f};
#pragma unroll
        for (int j = 0; j < 4; j++) acc[i][j] = {0.f, 0.f, 0.f, 0.f};
    }

#pragma unroll
    for (int mi = 0; mi < 4; mi++) {
        bf16x8 a0 = *(const bf16x8*)&qs[(wt + mi * 16 + l15) * 72 + quad * 8];
        bf16x8 a1 = *(const bf16x8*)&qs[(wt + mi * 16 + l15) * 72 + 32 + quad * 8];
        dacc[mi] = __builtin_amdgcn_mfma_f32_16x16x32_bf16(a0, ksf0, dacc[mi], 0, 0, 0);
        dacc[mi] = __builtin_amdgcn_mfma_f32_16x16x32_bf16(a1, ksf1, dacc[mi], 0, 0, 0);
#pragma unroll
        for (int nj = 0; nj < 4; nj++) {
            acc[mi][nj] = __builtin_amdgcn_mfma_f32_16x16x32_bf16(
                a0, bfr0[nj], acc[mi][nj], 0, 0, 0);
            acc[mi][nj] = __builtin_amdgcn_mfma_f32_16x16x32_bf16(
                a1, bfr1[nj], acc[mi][nj], 0, 0, 0);
        }
    }

    float coeff = *coeffp;
#pragma unroll
    for (int mi = 0; mi < 4; mi++) {
#pragma unroll
        for (int r = 0; r < 4; r++) {
            int s = s0 + wt + mi * 16 + quad * 4 + r;
            int t = b * S_ + s;
            float den = __shfl(dacc[mi][r], lane & 48) + 1e-6f;
            float gv = g[t];
            float w1 = gv / den + (1.f - gv) * coeff;
#pragma unroll
            for (int nj = 0; nj < 4; nj++) {
                int d = nj * 16 + l15;
                cmb[(size_t)t * H_ + n * 64 + d] = f2bf(acc[mi][nj][r] * w1);
            }
        }
    }
}

// ---------------------------------------------------------------------------
extern "C" void kernel_launch(void* const* d_in, const int* in_sizes, int n_in,
                              void* d_out, int out_size, void* d_ws, size_t ws_size,
                              hipStream_t stream) {
    const float* hs    = (const float*)d_in[0];
    const float* mask  = (const float*)d_in[1];
    const float* Wq    = (const float*)d_in[2];
    const float* bq    = (const float*)d_in[3];
    const float* Wk    = (const float*)d_in[4];
    const float* bk    = (const float*)d_in[5];
    const float* Wv    = (const float*)d_in[6];
    const float* bv    = (const float*)d_in[7];
    const float* Wo    = (const float*)d_in[8];
    const float* bo    = (const float*)d_in[9];
    const float* Wg    = (const float*)d_in[10];
    const float* bg    = (const float*)d_in[11];
    const float* decay = (const float*)d_in[12];
    const float* gate  = (const float*)d_in[13];
    float* out = (float*)d_out;

    // ---- workspace layout
    float* ws     = (float*)d_ws;
    float* kvb    = ws;                         // 262144
    float* ksum   = kvb + 262144;               // 4096
    float* gbuf   = ksum + 4096;                // 8192
    float* coeff  = gbuf + 8192;                // 64
    float* cosT   = coeff + 64;                 // 65536
    float* sinT   = cosT + 65536;               // 65536
    float* bqkv   = sinT + 65536;               // 3072 (+pad to 4096)
    float* kspart = bqkv + 4096;                // NCH*4096 = 65536
    float* kvpart = kspart + 65536;             // NCH*262144 = 4194304
    u16*   hsb    = (u16*)(kvpart + 4194304);   // T*1024
    u16*   Wt     = hsb + (size_t)T_ * H_;      // 4096*1024
    u16*   WoT    = Wt + (size_t)3072 * H_;
    u16*   qb     = Wt + (size_t)4096 * H_;     // T*1024 head-major
    u16*   kb     = qb + (size_t)T_ * H_;
    u16*   vb     = kb + (size_t)T_ * H_;
    u16*   cmb    = vb + (size_t)T_ * H_;

    pre_kernel<<<T_ + 1024 + 270, 256, 0, stream>>>(
        hs, Wg, bg, Wq, Wk, Wv, Wo, decay, gate, bq, bk, bv,
        hsb, gbuf, Wt, coeff, cosT, sinT, bqkv);

    gemm_qkv_kernel<<<dim3(3072 / 128, T_ / 256), 512, 0, stream>>>(
        hsb, Wt, bqkv, mask, cosT, sinT, qb, kb, vb);

    kv_part_kernel<<<dim3(B_ * NH, NCH), 256, 0, stream>>>(
        kb, vb, kvpart, kspart);
    reduce_part_kernel<<<(262144 + 4096 + 255) / 256, 256, 0, stream>>>(
        kvpart, kspart, kvb, ksum);

    combine_kernel<<<dim3(B_ * NH, S_ / 256), 256, 0, stream>>>(
        qb, kvb, ksum, gbuf, coeff, cmb);

    gemm_out_kernel<<<dim3(H_ / 128, T_ / 128), 256, 0, stream>>>(
        cmb, WoT, bo, out, H_);
}